// Round 3
// baseline (6657.671 us; speedup 1.0000x reference)
//
#include <hip/hip_runtime.h>

typedef _Float16 f16;
typedef unsigned short u16;
typedef unsigned int u32;

#define N_NODES 50000
#define N_EDGES 300000
#define ANNOT   200
#define KXP     208     // x K padded to multiple of 16
#define HID     256

// ---------- dtype helpers ----------
__device__ __forceinline__ float bf_bits_to_f32(u16 u) {
    union { u32 i; float f; } v; v.i = ((u32)u) << 16; return v.f;
}
__device__ __forceinline__ u16 f32_to_bf_bits(float f) {
    union { float f; u32 i; } v; v.f = f;
    u32 b = v.i;
    b += 0x7FFFu + ((b >> 16) & 1u);
    return (u16)(b >> 16);
}
// flag: 0 = inputs are bf16 (u16), 1 = inputs are float32
__device__ __forceinline__ float load_in(const void* p, long i, int flag) {
    if (flag) return ((const float*)p)[i];
    return bf_bits_to_f32(((const u16*)p)[i]);
}

// ---------- dtype probe ----------
// bf16-packed memory: low 16 bits of each word are a bf16 of ~N(0,1) -> exponent in [105,140].
// f32 memory: low 16 bits are mantissa noise -> exponent mostly outside that range.
__global__ void probe_dtype(const u32* __restrict__ xw, int* __restrict__ flag) {
    __shared__ int cnt;
    if (threadIdx.x == 0) cnt = 0;
    __syncthreads();
    int c = 0;
    for (int i = threadIdx.x; i < 256; i += 64) {
        u32 lo = xw[i] & 0xFFFFu;
        u32 e = (lo >> 7) & 0xFFu;
        if (e >= 105u && e <= 140u) c++;
    }
    atomicAdd(&cnt, c);
    __syncthreads();
    if (threadIdx.x == 0) flag[0] = (cnt > 128) ? 0 : 1;
}

// ---------- weight prep ----------
// Wr[k][n] (KXP x 256), zero-padded k>=200; from W_reduce [256,200] row-major.
__global__ void build_wr(const void* __restrict__ Wre, float* __restrict__ Wr,
                         const int* __restrict__ flagp) {
    const int flag = *flagp;
    const int i = blockIdx.x * 256 + threadIdx.x;
    if (i >= KXP * 256) return;
    const int k = i >> 8, n = i & 255;
    Wr[i] = (k < ANNOT) ? load_in(Wre, (long)n * ANNOT + k, flag) : 0.0f;
}

// Wg[s][k][n] fp32 copy of W_ggc (already [K,N] for m = h @ W_ggc[s])
__global__ void build_wggc(const void* __restrict__ Wg_in, float* __restrict__ Wg,
                           const int* __restrict__ flagp) {
    const int flag = *flagp;
    const int i = blockIdx.x * 256 + threadIdx.x;   // 8*256*256 total
    Wg[i] = load_in(Wg_in, i, flag);
}

// Bp[k][4*c+g], k in [0,512): g=0 r-pre, 1 z-pre, 2 i_n, 3 h_n
__global__ void build_bp(const void* __restrict__ Wih, const void* __restrict__ Whh,
                         float* __restrict__ Bp, const int* __restrict__ flagp) {
    const int flag = *flagp;
    const int i = blockIdx.x * 256 + threadIdx.x;   // 512*1024 total
    const int k = i >> 10;
    const int col = i & 1023;
    const int c = col >> 2;
    const int g = col & 3;
    float v = 0.0f;
    if (g == 0) {
        v = (k < 256) ? load_in(Wih, (long)c * 256 + k, flag)
                      : load_in(Whh, (long)c * 256 + (k - 256), flag);
    } else if (g == 1) {
        v = (k < 256) ? load_in(Wih, (long)(256 + c) * 256 + k, flag)
                      : load_in(Whh, (long)(256 + c) * 256 + (k - 256), flag);
    } else if (g == 2) {
        if (k < 256) v = load_in(Wih, (long)(512 + c) * 256 + k, flag);
    } else {
        if (k >= 256) v = load_in(Whh, (long)(512 + c) * 256 + (k - 256), flag);
    }
    Bp[i] = v;
}

// small fp32 params: brz[512]=b_ih+b_hh, bin[256], bhn[256], br0[256], wlin[512], blin[2]
__global__ void build_small(const void* b_ih, const void* b_hh, const void* b_red,
                            const void* W_lin, const void* b_lin,
                            float* __restrict__ sp, const int* __restrict__ flagp) {
    const int flag = *flagp;
    const int i = blockIdx.x * 256 + threadIdx.x;
    if (i < 512) {
        sp[i] = load_in(b_ih, i, flag) + load_in(b_hh, i, flag);                 // brz
    } else if (i < 768) {
        sp[i] = load_in(b_ih, 512 + (i - 512), flag);                            // bin
    } else if (i < 1024) {
        sp[i] = load_in(b_hh, 512 + (i - 768), flag);                            // bhn
    } else if (i < 1280) {
        sp[i] = load_in(b_red, i - 1024, flag);                                  // br0
    } else if (i < 1792) {
        sp[i] = load_in(W_lin, i - 1280, flag);                                  // wlin
    } else if (i < 1794) {
        sp[i] = load_in(b_lin, i - 1792, flag);                                  // blin
    }
}

// x_cvt [N, KXP] f16, zero-padded
__global__ void build_xcvt(const void* __restrict__ x, f16* __restrict__ xc,
                           const int* __restrict__ flagp) {
    const int flag = *flagp;
    const long i = (long)blockIdx.x * 256 + threadIdx.x;
    if (i >= (long)N_NODES * KXP) return;
    const long r = i / KXP;
    const int  k = (int)(i - r * KXP);
    xc[i] = (k < ANNOT) ? (f16)load_in(x, r * ANNOT + k, flag) : (f16)0.0f;
}

// ---------- CSR build ----------
__global__ void zero_i32(int* __restrict__ p, int n) {
    const int i = blockIdx.x * 256 + threadIdx.x;
    if (i < n) p[i] = 0;
}
__global__ void hist_kernel(const int* __restrict__ dst, int* __restrict__ deg, int n) {
    const int e = blockIdx.x * 256 + threadIdx.x;
    if (e < n) atomicAdd(&deg[dst[e]], 1);
}
__global__ void block_sum(const int* __restrict__ deg, int* __restrict__ partial, int n) {
    __shared__ int s[256];
    const int i = blockIdx.x * 256 + threadIdx.x;
    s[threadIdx.x] = (i < n) ? deg[i] : 0;
    __syncthreads();
    for (int off = 128; off > 0; off >>= 1) {
        if (threadIdx.x < off) s[threadIdx.x] += s[threadIdx.x + off];
        __syncthreads();
    }
    if (threadIdx.x == 0) partial[blockIdx.x] = s[0];
}
__global__ void scan_partials(int* __restrict__ partial, int nb, int* __restrict__ total_out) {
    __shared__ int s[256];
    const int t = threadIdx.x;
    s[t] = (t < nb) ? partial[t] : 0;
    __syncthreads();
    for (int off = 1; off < 256; off <<= 1) {
        int v = (t >= off) ? s[t - off] : 0;
        __syncthreads();
        s[t] += v;
        __syncthreads();
    }
    if (t < nb) partial[t] = (t == 0) ? 0 : s[t - 1];
    if (t == 0) *total_out = s[255];
}
__global__ void scan_block(const int* __restrict__ deg, const int* __restrict__ partial,
                           int* __restrict__ row_off, int* __restrict__ cursor, int n) {
    __shared__ int s[256];
    const int t = threadIdx.x;
    const int i = blockIdx.x * 256 + t;
    const int v = (i < n) ? deg[i] : 0;
    s[t] = v;
    __syncthreads();
    for (int off = 1; off < 256; off <<= 1) {
        int u = (t >= off) ? s[t - off] : 0;
        __syncthreads();
        s[t] += u;
        __syncthreads();
    }
    if (i < n) {
        const int v0 = partial[blockIdx.x] + s[t] - v;
        row_off[i] = v0;
        cursor[i]  = v0;
    }
}
__global__ void fill_kernel(const int* __restrict__ src, const int* __restrict__ dst,
                            int* __restrict__ cursor, int* __restrict__ csr, int n) {
    const int e = blockIdx.x * 256 + threadIdx.x;
    if (e < n) {
        const int p = atomicAdd(&cursor[dst[e]], 1);
        csr[p] = src[e];
    }
}

// ---------- GEMM: C[M,N](f16) = A[M,K](f16) * B[K,N](f32) + bias ----------
// 64x64 tile, 16x16 threads, 4x4 per thread, K%16==0.
__global__ void gemm_f16(const f16* __restrict__ A, int lda,
                         const float* __restrict__ B, int ldb,
                         f16* __restrict__ C, int ldc,
                         const float* __restrict__ bias,
                         int M, int N, int K)
{
    __shared__ float As[16][68];   // [k][row]
    __shared__ float Bs[16][68];   // [k][col]
    const int tid = threadIdx.x;
    const int tx = tid & 15, ty = tid >> 4;
    const int bm = blockIdx.x * 64;
    const int bn = blockIdx.y * 64;
    float acc[4][4];
#pragma unroll
    for (int i = 0; i < 4; ++i)
#pragma unroll
        for (int j = 0; j < 4; ++j) acc[i][j] = 0.0f;

    const int arow = tid >> 2;            // 0..63
    const int ak   = (tid & 3) * 4;       // 0,4,8,12
    int ar = bm + arow; if (ar > M - 1) ar = M - 1;
    const int bcol = tid & 63;
    const int brow = (tid >> 6) * 4;

    for (int k0 = 0; k0 < K; k0 += 16) {
#pragma unroll
        for (int i = 0; i < 4; ++i)
            As[ak + i][arow] = (float)A[(long)ar * lda + k0 + ak + i];
#pragma unroll
        for (int i = 0; i < 4; ++i)
            Bs[brow + i][bcol] = B[(long)(k0 + brow + i) * ldb + bn + bcol];
        __syncthreads();
#pragma unroll
        for (int k = 0; k < 16; ++k) {
            float av[4], bv[4];
#pragma unroll
            for (int i = 0; i < 4; ++i) av[i] = As[k][ty * 4 + i];
#pragma unroll
            for (int j = 0; j < 4; ++j) bv[j] = Bs[k][tx * 4 + j];
#pragma unroll
            for (int i = 0; i < 4; ++i)
#pragma unroll
                for (int j = 0; j < 4; ++j) acc[i][j] += av[i] * bv[j];
        }
        __syncthreads();
    }
#pragma unroll
    for (int i = 0; i < 4; ++i) {
        const int r = bm + ty * 4 + i;
        if (r < M) {
#pragma unroll
            for (int j = 0; j < 4; ++j) {
                const int c = bn + tx * 4 + j;
                const float bv = bias ? bias[c] : 0.0f;
                C[(long)r * ldc + c] = (f16)(acc[i][j] + bv);
            }
        }
    }
}

// ---------- gates GEMM + fused GRU ----------
// A = [agg | h] over K=512, B = Bp [512,1024] (col = 4*ch+gate), epilogue GRU.
__global__ void gemm_gates(const f16* __restrict__ agg, const f16* __restrict__ hcur,
                           const float* __restrict__ Bp,
                           f16* __restrict__ hnxt,
                           const float* __restrict__ brz, const float* __restrict__ bin,
                           const float* __restrict__ bhn, int M)
{
    __shared__ float As[16][68];
    __shared__ float Bs[16][68];
    const int tid = threadIdx.x;
    const int tx = tid & 15, ty = tid >> 4;
    const int bm = blockIdx.x * 64;
    const int bn = blockIdx.y * 64;      // gate-col base; channel base = bn/4
    float acc[4][4];
#pragma unroll
    for (int i = 0; i < 4; ++i)
#pragma unroll
        for (int j = 0; j < 4; ++j) acc[i][j] = 0.0f;

    const int arow = tid >> 2;
    const int ak   = (tid & 3) * 4;
    int ar = bm + arow; if (ar > M - 1) ar = M - 1;
    const int bcol = tid & 63;
    const int brow = (tid >> 6) * 4;

    for (int k0 = 0; k0 < 512; k0 += 16) {
#pragma unroll
        for (int i = 0; i < 4; ++i) {
            const int kk = k0 + ak + i;
            const float v = (kk < 256) ? (float)agg[(long)ar * 256 + kk]
                                       : (float)hcur[(long)ar * 256 + (kk - 256)];
            As[ak + i][arow] = v;
        }
#pragma unroll
        for (int i = 0; i < 4; ++i)
            Bs[brow + i][bcol] = Bp[(long)(k0 + brow + i) * 1024 + bn + bcol];
        __syncthreads();
#pragma unroll
        for (int k = 0; k < 16; ++k) {
            float av[4], bv[4];
#pragma unroll
            for (int i = 0; i < 4; ++i) av[i] = As[k][ty * 4 + i];
#pragma unroll
            for (int j = 0; j < 4; ++j) bv[j] = Bs[k][tx * 4 + j];
#pragma unroll
            for (int i = 0; i < 4; ++i)
#pragma unroll
                for (int j = 0; j < 4; ++j) acc[i][j] += av[i] * bv[j];
        }
        __syncthreads();
    }

    const int ch = (bn >> 2) + tx;       // channel this thread owns (cols 4ch..4ch+3)
    const float b_r = brz[ch], b_z = brz[256 + ch];
    const float b_in = bin[ch], b_hn = bhn[ch];
#pragma unroll
    for (int i = 0; i < 4; ++i) {
        const int r = bm + ty * 4 + i;
        if (r < M) {
            const float pr = acc[i][0] + b_r;
            const float pz = acc[i][1] + b_z;
            const float rg = 1.0f / (1.0f + expf(-pr));
            const float zg = 1.0f / (1.0f + expf(-pz));
            const float nn = tanhf(acc[i][2] + b_in + rg * (acc[i][3] + b_hn));
            const float ho = (float)hcur[(long)r * 256 + ch];
            hnxt[(long)r * 256 + ch] = (f16)((1.0f - zg) * nn + zg * ho);
        }
    }
}

// ---------- aggregate: agg[v] = sum_{e: dst=v} m[src[e]] ----------
__global__ void aggregate(const f16* __restrict__ m, const int* __restrict__ row_off,
                          const int* __restrict__ csr, f16* __restrict__ agg)
{
    const int node = blockIdx.x * 4 + (threadIdx.x >> 6);
    const int lane = threadIdx.x & 63;
    if (node >= N_NODES) return;
    const int e0 = row_off[node], e1 = row_off[node + 1];
    float a0 = 0.0f, a1 = 0.0f, a2 = 0.0f, a3 = 0.0f;
    for (int e = e0; e < e1; ++e) {
        const int s = csr[e];
        const f16* p = m + (long)s * 256 + lane * 4;
        a0 += (float)p[0]; a1 += (float)p[1]; a2 += (float)p[2]; a3 += (float)p[3];
    }
    f16* o = agg + (long)node * 256 + lane * 4;
    o[0] = (f16)a0; o[1] = (f16)a1; o[2] = (f16)a2; o[3] = (f16)a3;
}

// ---------- final head ----------
__global__ void final_kernel(const f16* __restrict__ h, const float* __restrict__ wlin,
                             const float* __restrict__ blin, void* __restrict__ out,
                             const int* __restrict__ flagp)
{
    const int flag = *flagp;
    const int node = blockIdx.x * 4 + (threadIdx.x >> 6);
    const int lane = threadIdx.x & 63;
    if (node >= N_NODES) return;
    const f16* hp = h + (long)node * 256;
    float a0 = 0.0f, a1 = 0.0f;
#pragma unroll
    for (int u = 0; u < 4; ++u) {
        const int c = lane * 4 + u;
        float hv = (float)hp[c];
        hv = hv > 0.0f ? hv : 0.0f;
        a0 += hv * wlin[c];
        a1 += hv * wlin[256 + c];
    }
#pragma unroll
    for (int off = 32; off > 0; off >>= 1) {
        a0 += __shfl_down(a0, off);
        a1 += __shfl_down(a1, off);
    }
    if (lane == 0) {
        a0 += blin[0];
        a1 += blin[1];
        const float mx  = fmaxf(a0, a1);
        const float lse = mx + logf(expf(a0 - mx) + expf(a1 - mx));
        const float o0 = a0 - lse, o1 = a1 - lse;
        if (flag) {
            ((float*)out)[(long)node * 2]     = o0;
            ((float*)out)[(long)node * 2 + 1] = o1;
        } else {
            ((u16*)out)[(long)node * 2]     = f32_to_bf_bits(o0);
            ((u16*)out)[(long)node * 2 + 1] = f32_to_bf_bits(o1);
        }
    }
}

extern "C" void kernel_launch(void* const* d_in, const int* in_sizes, int n_in,
                              void* d_out, int out_size, void* d_ws, size_t ws_size,
                              hipStream_t stream)
{
    (void)in_sizes; (void)n_in; (void)out_size; (void)ws_size;
    const void* x        = d_in[0];
    const int*  ei       = (const int*)d_in[1];
    const void* W_reduce = d_in[3];
    const void* b_reduce = d_in[4];
    const void* W_ggc    = d_in[5];
    const void* W_ih     = d_in[6];
    const void* W_hh     = d_in[7];
    const void* b_ih     = d_in[8];
    const void* b_hh     = d_in[9];
    const void* W_lin    = d_in[10];
    const void* b_lin    = d_in[11];
    const int* src = ei;
    const int* dst = ei + N_EDGES;

    char* w = (char*)d_ws;
    auto carve = [&](size_t bytes) -> char* {
        char* p = w;
        w += (bytes + 255) & ~(size_t)255;
        return p;
    };
    f16*   h_a   = (f16*)carve((size_t)N_NODES * 256 * 2);
    f16*   h_b   = (f16*)carve((size_t)N_NODES * 256 * 2);
    f16*   agg   = (f16*)carve((size_t)N_NODES * 256 * 2);
    f16*   m     = (f16*)carve((size_t)N_NODES * 256 * 2);   // union with x_cvt [N,KXP]
    f16*   x_cvt = m;
    float* Wr    = (float*)carve((size_t)KXP * 256 * 4);
    float* Wg    = (float*)carve((size_t)8 * 256 * 256 * 4);
    float* Bp    = (float*)carve((size_t)512 * 1024 * 4);
    float* sp    = (float*)carve(2048 * 4);   // brz|bin|bhn|br0|wlin|blin
    int*   flag  = (int*)carve(256);
    int* deg     = (int*)carve((size_t)N_NODES * 4);
    int* row_off = (int*)carve((size_t)(N_NODES + 1) * 4);
    int* cursor  = (int*)carve((size_t)N_NODES * 4);
    int* csr     = (int*)carve((size_t)N_EDGES * 4);
    int* partial = (int*)carve(256 * 4);

    float* brz  = sp;
    float* bin  = sp + 512;
    float* bhn  = sp + 768;
    float* br0  = sp + 1024;
    float* wlin = sp + 1280;
    float* blin = sp + 1792;

    probe_dtype<<<1, 64, 0, stream>>>((const u32*)x, flag);

    build_wr<<<(KXP * 256 + 255) / 256, 256, 0, stream>>>(W_reduce, Wr, flag);
    build_wggc<<<(8 * 256 * 256) / 256, 256, 0, stream>>>(W_ggc, Wg, flag);
    build_bp<<<(512 * 1024) / 256, 256, 0, stream>>>(W_ih, W_hh, Bp, flag);
    build_small<<<8, 256, 0, stream>>>(b_ih, b_hh, b_reduce, W_lin, b_lin, sp, flag);
    build_xcvt<<<(int)(((long)N_NODES * KXP + 255) / 256), 256, 0, stream>>>(x, x_cvt, flag);

    zero_i32<<<196, 256, 0, stream>>>(deg, N_NODES);
    hist_kernel<<<(N_EDGES + 255) / 256, 256, 0, stream>>>(dst, deg, N_EDGES);
    block_sum<<<196, 256, 0, stream>>>(deg, partial, N_NODES);
    scan_partials<<<1, 256, 0, stream>>>(partial, 196, row_off + N_NODES);
    scan_block<<<196, 256, 0, stream>>>(deg, partial, row_off, cursor, N_NODES);
    fill_kernel<<<(N_EDGES + 255) / 256, 256, 0, stream>>>(src, dst, cursor, csr, N_EDGES);

    // h0 = x @ W_reduce^T + b_reduce -> h_a
    gemm_f16<<<dim3(782, 4), 256, 0, stream>>>(x_cvt, KXP, Wr, 256, h_a, 256, br0,
                                               N_NODES, 256, KXP);

    for (int s = 0; s < 8; ++s) {
        const f16* hcur = (s & 1) ? h_b : h_a;
        f16*       hnxt = (s & 1) ? h_a : h_b;
        gemm_f16<<<dim3(782, 4), 256, 0, stream>>>(hcur, 256, Wg + (size_t)s * 65536, 256,
                                                   m, 256, (const float*)nullptr,
                                                   N_NODES, 256, 256);
        aggregate<<<12500, 256, 0, stream>>>(m, row_off, csr, agg);
        gemm_gates<<<dim3(782, 16), 256, 0, stream>>>(agg, hcur, Bp, hnxt, brz, bin, bhn, N_NODES);
    }

    // after s=7, result is in h_a
    final_kernel<<<12500, 256, 0, stream>>>(h_a, wlin, blin, d_out, flag);
}

// Round 5
// 1834.016 us; speedup vs baseline: 3.6301x; 3.6301x over previous
//
#include <hip/hip_runtime.h>

typedef _Float16 f16;
typedef unsigned short u16;
typedef unsigned int u32;
typedef _Float16 f16x8 __attribute__((ext_vector_type(8)));
typedef float    floatx4 __attribute__((ext_vector_type(4)));

#define N_NODES 50000
#define N_EDGES 300000
#define ANNOT   200
#define KXP     224     // x K padded to multiple of 32
#define HID     256

// MFMA wrapper: real builtin on device pass, stub on host pass (builtin is
// undeclared during hipcc's host compilation and would kill the build).
__device__ __forceinline__ floatx4 mfma_16x16x32_f16(f16x8 a, f16x8 b, floatx4 c) {
#if defined(__HIP_DEVICE_COMPILE__)
    return __builtin_amdgcn_mfma_f32_16x16x32_f16(a, b, c, 0, 0, 0);
#else
    return c;
#endif
}

// ---------- dtype helpers ----------
__device__ __forceinline__ float bf_bits_to_f32(u16 u) {
    union { u32 i; float f; } v; v.i = ((u32)u) << 16; return v.f;
}
__device__ __forceinline__ u16 f32_to_bf_bits(float f) {
    union { float f; u32 i; } v; v.f = f;
    u32 b = v.i;
    b += 0x7FFFu + ((b >> 16) & 1u);
    return (u16)(b >> 16);
}
// flag: 0 = inputs are bf16 (u16), 1 = inputs are float32
__device__ __forceinline__ float load_in(const void* p, long i, int flag) {
    if (flag) return ((const float*)p)[i];
    return bf_bits_to_f32(((const u16*)p)[i]);
}

// ---------- dtype probe ----------
__global__ void probe_dtype(const u32* __restrict__ xw, int* __restrict__ flag) {
    __shared__ int cnt;
    if (threadIdx.x == 0) cnt = 0;
    __syncthreads();
    int c = 0;
    for (int i = threadIdx.x; i < 256; i += 64) {
        u32 lo = xw[i] & 0xFFFFu;
        u32 e = (lo >> 7) & 0xFFu;
        if (e >= 105u && e <= 140u) c++;
    }
    atomicAdd(&cnt, c);
    __syncthreads();
    if (threadIdx.x == 0) flag[0] = (cnt > 128) ? 0 : 1;
}

// ---------- weight prep (all f16, B^T layouts) ----------
// WrT[n][k] (256 x KXP), from W_reduce [256,200] row-major (already [N,K])
__global__ void build_wrT(const void* __restrict__ Wre, f16* __restrict__ WrT,
                          const int* __restrict__ flagp) {
    const int flag = *flagp;
    const int i = blockIdx.x * 256 + threadIdx.x;
    if (i >= 256 * KXP) return;
    const int n = i / KXP, k = i - n * KXP;
    WrT[i] = (k < ANNOT) ? (f16)load_in(Wre, (long)n * ANNOT + k, flag) : (f16)0.0f;
}

// WgT[s][n][k] = W_ggc[s][k][n]
__global__ void build_wgT(const void* __restrict__ Wg_in, f16* __restrict__ WgT,
                          const int* __restrict__ flagp) {
    const int flag = *flagp;
    const int i = blockIdx.x * 256 + threadIdx.x;   // 8*256*256
    const int s = i >> 16;
    const int n = (i >> 8) & 255;
    const int k = i & 255;
    WgT[i] = (f16)load_in(Wg_in, (s << 16) + (k << 8) + n, flag);
}

// Bb[1024][512]; row = chblk*128 + g*32 + c, channel = chblk*32+c.
// g=0: r-row of [Wih|Whh]; g=1: z-row; g=2: [Wih_n | 0]; g=3: [0 | Whh_n]
__global__ void build_bb(const void* __restrict__ Wih, const void* __restrict__ Whh,
                         f16* __restrict__ Bb, const int* __restrict__ flagp) {
    const int flag = *flagp;
    const int i = blockIdx.x * 256 + threadIdx.x;   // 1024*512
    const int row = i >> 9;
    const int k = i & 511;
    const int chblk = row >> 7;
    const int r = row & 127;
    const int g = r >> 5;
    const int c = r & 31;
    const int ch = chblk * 32 + c;
    float v = 0.0f;
    if (g == 0) {
        v = (k < 256) ? load_in(Wih, (long)ch * 256 + k, flag)
                      : load_in(Whh, (long)ch * 256 + (k - 256), flag);
    } else if (g == 1) {
        v = (k < 256) ? load_in(Wih, (long)(256 + ch) * 256 + k, flag)
                      : load_in(Whh, (long)(256 + ch) * 256 + (k - 256), flag);
    } else if (g == 2) {
        if (k < 256) v = load_in(Wih, (long)(512 + ch) * 256 + k, flag);
    } else {
        if (k >= 256) v = load_in(Whh, (long)(512 + ch) * 256 + (k - 256), flag);
    }
    Bb[i] = (f16)v;
}

// small fp32 params: brz[512]=b_ih+b_hh, bin[256], bhn[256], br0[256], wlin[512], blin[2]
__global__ void build_small(const void* b_ih, const void* b_hh, const void* b_red,
                            const void* W_lin, const void* b_lin,
                            float* __restrict__ sp, const int* __restrict__ flagp) {
    const int flag = *flagp;
    const int i = blockIdx.x * 256 + threadIdx.x;
    if (i < 512) {
        sp[i] = load_in(b_ih, i, flag) + load_in(b_hh, i, flag);
    } else if (i < 768) {
        sp[i] = load_in(b_ih, 512 + (i - 512), flag);
    } else if (i < 1024) {
        sp[i] = load_in(b_hh, 512 + (i - 768), flag);
    } else if (i < 1280) {
        sp[i] = load_in(b_red, i - 1024, flag);
    } else if (i < 1792) {
        sp[i] = load_in(W_lin, i - 1280, flag);
    } else if (i < 1794) {
        sp[i] = load_in(b_lin, i - 1792, flag);
    }
}

// x_cvt [N, KXP] f16, zero-padded
__global__ void build_xcvt(const void* __restrict__ x, f16* __restrict__ xc,
                           const int* __restrict__ flagp) {
    const int flag = *flagp;
    const long i = (long)blockIdx.x * 256 + threadIdx.x;
    if (i >= (long)N_NODES * KXP) return;
    const long r = i / KXP;
    const int  k = (int)(i - r * KXP);
    xc[i] = (k < ANNOT) ? (f16)load_in(x, r * ANNOT + k, flag) : (f16)0.0f;
}

// ---------- CSR build ----------
__global__ void zero_i32(int* __restrict__ p, int n) {
    const int i = blockIdx.x * 256 + threadIdx.x;
    if (i < n) p[i] = 0;
}
__global__ void hist_kernel(const int* __restrict__ dst, int* __restrict__ deg, int n) {
    const int e = blockIdx.x * 256 + threadIdx.x;
    if (e < n) atomicAdd(&deg[dst[e]], 1);
}
__global__ void block_sum(const int* __restrict__ deg, int* __restrict__ partial, int n) {
    __shared__ int s[256];
    const int i = blockIdx.x * 256 + threadIdx.x;
    s[threadIdx.x] = (i < n) ? deg[i] : 0;
    __syncthreads();
    for (int off = 128; off > 0; off >>= 1) {
        if (threadIdx.x < off) s[threadIdx.x] += s[threadIdx.x + off];
        __syncthreads();
    }
    if (threadIdx.x == 0) partial[blockIdx.x] = s[0];
}
__global__ void scan_partials(int* __restrict__ partial, int nb, int* __restrict__ total_out) {
    __shared__ int s[256];
    const int t = threadIdx.x;
    s[t] = (t < nb) ? partial[t] : 0;
    __syncthreads();
    for (int off = 1; off < 256; off <<= 1) {
        int v = (t >= off) ? s[t - off] : 0;
        __syncthreads();
        s[t] += v;
        __syncthreads();
    }
    if (t < nb) partial[t] = (t == 0) ? 0 : s[t - 1];
    if (t == 0) *total_out = s[255];
}
__global__ void scan_block(const int* __restrict__ deg, const int* __restrict__ partial,
                           int* __restrict__ row_off, int* __restrict__ cursor, int n) {
    __shared__ int s[256];
    const int t = threadIdx.x;
    const int i = blockIdx.x * 256 + t;
    const int v = (i < n) ? deg[i] : 0;
    s[t] = v;
    __syncthreads();
    for (int off = 1; off < 256; off <<= 1) {
        int u = (t >= off) ? s[t - off] : 0;
        __syncthreads();
        s[t] += u;
        __syncthreads();
    }
    if (i < n) {
        const int v0 = partial[blockIdx.x] + s[t] - v;
        row_off[i] = v0;
        cursor[i]  = v0;
    }
}
__global__ void fill_kernel(const int* __restrict__ src, const int* __restrict__ dst,
                            int* __restrict__ cursor, int* __restrict__ csr, int n) {
    const int e = blockIdx.x * 256 + threadIdx.x;
    if (e < n) {
        const int p = atomicAdd(&cursor[dst[e]], 1);
        csr[p] = src[e];
    }
}

// ---------- MFMA GEMM: C[M,N](f16) = A[M,K](f16) * Bt[N,K]^T + bias ----------
// 128x128 tile, 4 waves, BK=32. K%32==0, N%128==0, M tail clamp+predicate.
__global__ __launch_bounds__(256) void mgemm(
    const f16* __restrict__ A, int lda,
    const f16* __restrict__ Bt, int ldb,
    f16* __restrict__ C, int ldc,
    const float* __restrict__ bias,
    int M, int N, int K)
{
    __shared__ __attribute__((aligned(16))) f16 As[128 * 32];
    __shared__ __attribute__((aligned(16))) f16 Bs[128 * 32];
    const int tid  = threadIdx.x;
    const int lane = tid & 63;
    const int wave = tid >> 6;
    const int bm = blockIdx.x * 128;
    const int bn = blockIdx.y * 128;
    const int wm = (wave >> 1) * 64;
    const int wn = (wave & 1) * 64;
    const int quad = lane >> 4;
    const int l16  = lane & 15;

    floatx4 acc[4][4];
#pragma unroll
    for (int i = 0; i < 4; ++i)
#pragma unroll
        for (int j = 0; j < 4; ++j) acc[i][j] = (floatx4)(0.0f);

    for (int k0 = 0; k0 < K; k0 += 32) {
        __syncthreads();
#pragma unroll
        for (int it = 0; it < 2; ++it) {
            const int ci  = it * 256 + tid;   // 0..511
            const int row = ci >> 2;
            const int cg  = ci & 3;
            int ga = bm + row; if (ga > M - 1) ga = M - 1;
            *(f16x8*)(As + ci * 8) = *(const f16x8*)(A + (long)ga * lda + k0 + cg * 8);
            *(f16x8*)(Bs + ci * 8) = *(const f16x8*)(Bt + (long)(bn + row) * ldb + k0 + cg * 8);
        }
        __syncthreads();

        f16x8 af[4], bfv[4];
#pragma unroll
        for (int i = 0; i < 4; ++i) {
            af[i]  = *(const f16x8*)(As + (wm + i * 16 + l16) * 32 + quad * 8);
            bfv[i] = *(const f16x8*)(Bs + (wn + i * 16 + l16) * 32 + quad * 8);
        }
#pragma unroll
        for (int i = 0; i < 4; ++i)
#pragma unroll
            for (int j = 0; j < 4; ++j)
                acc[i][j] = mfma_16x16x32_f16(af[i], bfv[j], acc[i][j]);
    }

#pragma unroll
    for (int i = 0; i < 4; ++i) {
        const int r0 = bm + wm + i * 16 + quad * 4;
#pragma unroll
        for (int j = 0; j < 4; ++j) {
            const int col = bn + wn + j * 16 + l16;
            const float bv = bias ? bias[col] : 0.0f;
#pragma unroll
            for (int v = 0; v < 4; ++v) {
                const int r = r0 + v;
                if (r < M) C[(long)r * ldc + col] = (f16)(acc[i][j][v] + bv);
            }
        }
    }
}

// ---------- MFMA gates GEMM + fully fused GRU ----------
// A = [agg|h] (K=512), B = Bb[1024][512] with row = chblk*128 + gate*32 + c.
// Block: 128 rows x 32 channels (x4 gates). Wave: 64 rows x 16 channels; j-tile = gate.
__global__ __launch_bounds__(256) void gemm_gates(
    const f16* __restrict__ agg, const f16* __restrict__ hcur,
    const f16* __restrict__ Bb, f16* __restrict__ hnxt,
    const float* __restrict__ brz, const float* __restrict__ bin,
    const float* __restrict__ bhn, int M)
{
    __shared__ __attribute__((aligned(16))) f16 As[128 * 32];
    __shared__ __attribute__((aligned(16))) f16 Bs[128 * 32];
    const int tid  = threadIdx.x;
    const int lane = tid & 63;
    const int wave = tid >> 6;
    const int bm = blockIdx.x * 128;
    const int by = blockIdx.y;            // channel block (32 ch)
    const int wm  = (wave >> 1) * 64;
    const int chh = (wave & 1) * 16;      // channel half within block
    const int quad = lane >> 4;
    const int l16  = lane & 15;

    floatx4 acc[4][4];
#pragma unroll
    for (int i = 0; i < 4; ++i)
#pragma unroll
        for (int j = 0; j < 4; ++j) acc[i][j] = (floatx4)(0.0f);

    for (int k0 = 0; k0 < 512; k0 += 32) {
        __syncthreads();
#pragma unroll
        for (int it = 0; it < 2; ++it) {
            const int ci  = it * 256 + tid;
            const int row = ci >> 2;
            const int cg  = ci & 3;
            int ga = bm + row; if (ga > M - 1) ga = M - 1;
            const int kk = k0 + cg * 8;
            const f16* ap = (kk < 256) ? (agg + (long)ga * 256 + kk)
                                       : (hcur + (long)ga * 256 + (kk - 256));
            *(f16x8*)(As + ci * 8) = *(const f16x8*)ap;
            *(f16x8*)(Bs + ci * 8) = *(const f16x8*)(Bb + (long)(by * 128 + row) * 512 + kk);
        }
        __syncthreads();

        f16x8 af[4], bfv[4];
#pragma unroll
        for (int i = 0; i < 4; ++i) {
            af[i]  = *(const f16x8*)(As + (wm + i * 16 + l16) * 32 + quad * 8);
            bfv[i] = *(const f16x8*)(Bs + (i * 32 + chh + l16) * 32 + quad * 8);
        }
#pragma unroll
        for (int i = 0; i < 4; ++i)
#pragma unroll
            for (int j = 0; j < 4; ++j)
                acc[i][j] = mfma_16x16x32_f16(af[i], bfv[j], acc[i][j]);
    }

    // epilogue: lane owns channel ch; acc[i][g][v] = gate g preact at row r0+v
    const int ch = by * 32 + chh + l16;
    const float b_r  = brz[ch];
    const float b_z  = brz[256 + ch];
    const float b_in = bin[ch];
    const float b_hn = bhn[ch];
#pragma unroll
    for (int i = 0; i < 4; ++i) {
        const int r0 = bm + wm + i * 16 + quad * 4;
#pragma unroll
        for (int v = 0; v < 4; ++v) {
            const int r = r0 + v;
            if (r < M) {
                const float rg = 1.0f / (1.0f + expf(-(acc[i][0][v] + b_r)));
                const float zg = 1.0f / (1.0f + expf(-(acc[i][1][v] + b_z)));
                const float nn = tanhf(acc[i][2][v] + b_in + rg * (acc[i][3][v] + b_hn));
                const float ho = (float)hcur[(long)r * 256 + ch];
                hnxt[(long)r * 256 + ch] = (f16)((1.0f - zg) * nn + zg * ho);
            }
        }
    }
}

// ---------- aggregate: agg[v] = sum_{e: dst=v} m[src[e]] ----------
__global__ __launch_bounds__(256) void aggregate(
    const f16* __restrict__ m, const int* __restrict__ row_off,
    const int* __restrict__ csr, f16* __restrict__ agg)
{
    const int node = blockIdx.x * 4 + (threadIdx.x >> 6);
    const int lane = threadIdx.x & 63;
    if (node >= N_NODES) return;
    const int e0 = row_off[node], e1 = row_off[node + 1];
    float a0 = 0.0f, a1 = 0.0f, a2 = 0.0f, a3 = 0.0f;
    for (int e = e0; e < e1; ++e) {
        const int s = csr[e];
        const f16* p = m + (long)s * 256 + lane * 4;
        a0 += (float)p[0]; a1 += (float)p[1]; a2 += (float)p[2]; a3 += (float)p[3];
    }
    f16* o = agg + (long)node * 256 + lane * 4;
    o[0] = (f16)a0; o[1] = (f16)a1; o[2] = (f16)a2; o[3] = (f16)a3;
}

// ---------- final head ----------
__global__ __launch_bounds__(256) void final_kernel(
    const f16* __restrict__ h, const float* __restrict__ wlin,
    const float* __restrict__ blin, void* __restrict__ out,
    const int* __restrict__ flagp)
{
    const int flag = *flagp;
    const int node = blockIdx.x * 4 + (threadIdx.x >> 6);
    const int lane = threadIdx.x & 63;
    if (node >= N_NODES) return;
    const f16* hp = h + (long)node * 256;
    float a0 = 0.0f, a1 = 0.0f;
#pragma unroll
    for (int u = 0; u < 4; ++u) {
        const int c = lane * 4 + u;
        float hv = (float)hp[c];
        hv = hv > 0.0f ? hv : 0.0f;
        a0 += hv * wlin[c];
        a1 += hv * wlin[256 + c];
    }
#pragma unroll
    for (int off = 32; off > 0; off >>= 1) {
        a0 += __shfl_down(a0, off);
        a1 += __shfl_down(a1, off);
    }
    if (lane == 0) {
        a0 += blin[0];
        a1 += blin[1];
        const float mx  = fmaxf(a0, a1);
        const float lse = mx + logf(expf(a0 - mx) + expf(a1 - mx));
        const float o0 = a0 - lse, o1 = a1 - lse;
        if (flag) {
            ((float*)out)[(long)node * 2]     = o0;
            ((float*)out)[(long)node * 2 + 1] = o1;
        } else {
            ((u16*)out)[(long)node * 2]     = f32_to_bf_bits(o0);
            ((u16*)out)[(long)node * 2 + 1] = f32_to_bf_bits(o1);
        }
    }
}

extern "C" void kernel_launch(void* const* d_in, const int* in_sizes, int n_in,
                              void* d_out, int out_size, void* d_ws, size_t ws_size,
                              hipStream_t stream)
{
    (void)in_sizes; (void)n_in; (void)out_size; (void)ws_size;
    const void* x        = d_in[0];
    const int*  ei       = (const int*)d_in[1];
    const void* W_reduce = d_in[3];
    const void* b_reduce = d_in[4];
    const void* W_ggc    = d_in[5];
    const void* W_ih     = d_in[6];
    const void* W_hh     = d_in[7];
    const void* b_ih     = d_in[8];
    const void* b_hh     = d_in[9];
    const void* W_lin    = d_in[10];
    const void* b_lin    = d_in[11];
    const int* src = ei;
    const int* dst = ei + N_EDGES;

    char* w = (char*)d_ws;
    auto carve = [&](size_t bytes) -> char* {
        char* p = w;
        w += (bytes + 255) & ~(size_t)255;
        return p;
    };
    f16*   h_a   = (f16*)carve((size_t)N_NODES * 256 * 2);
    f16*   h_b   = (f16*)carve((size_t)N_NODES * 256 * 2);
    f16*   agg   = (f16*)carve((size_t)N_NODES * 256 * 2);
    f16*   m     = (f16*)carve((size_t)N_NODES * 256 * 2);   // union with x_cvt [N,KXP]
    f16*   x_cvt = m;
    f16*   WrT   = (f16*)carve((size_t)256 * KXP * 2);
    f16*   WgT   = (f16*)carve((size_t)8 * 256 * 256 * 2);
    f16*   Bb    = (f16*)carve((size_t)1024 * 512 * 2);
    float* sp    = (float*)carve(2048 * 4);
    int*   flag  = (int*)carve(256);
    int* deg     = (int*)carve((size_t)N_NODES * 4);
    int* row_off = (int*)carve((size_t)(N_NODES + 1) * 4);
    int* cursor  = (int*)carve((size_t)N_NODES * 4);
    int* csr     = (int*)carve((size_t)N_EDGES * 4);
    int* partial = (int*)carve(256 * 4);

    float* brz  = sp;
    float* bin  = sp + 512;
    float* bhn  = sp + 768;
    float* br0  = sp + 1024;
    float* wlin = sp + 1280;
    float* blin = sp + 1792;

    probe_dtype<<<1, 64, 0, stream>>>((const u32*)x, flag);

    build_wrT<<<(256 * KXP + 255) / 256, 256, 0, stream>>>(W_reduce, WrT, flag);
    build_wgT<<<(8 * 256 * 256) / 256, 256, 0, stream>>>(W_ggc, WgT, flag);
    build_bb<<<(1024 * 512) / 256, 256, 0, stream>>>(W_ih, W_hh, Bb, flag);
    build_small<<<8, 256, 0, stream>>>(b_ih, b_hh, b_reduce, W_lin, b_lin, sp, flag);
    build_xcvt<<<(int)(((long)N_NODES * KXP + 255) / 256), 256, 0, stream>>>(x, x_cvt, flag);

    zero_i32<<<196, 256, 0, stream>>>(deg, N_NODES);
    hist_kernel<<<(N_EDGES + 255) / 256, 256, 0, stream>>>(dst, deg, N_EDGES);
    block_sum<<<196, 256, 0, stream>>>(deg, partial, N_NODES);
    scan_partials<<<1, 256, 0, stream>>>(partial, 196, row_off + N_NODES);
    scan_block<<<196, 256, 0, stream>>>(deg, partial, row_off, cursor, N_NODES);
    fill_kernel<<<(N_EDGES + 255) / 256, 256, 0, stream>>>(src, dst, cursor, csr, N_EDGES);

    // h0 = x @ W_reduce^T + b_reduce -> h_a
    mgemm<<<dim3(391, 2), 256, 0, stream>>>(x_cvt, KXP, WrT, KXP, h_a, 256, br0,
                                            N_NODES, 256, KXP);

    for (int s = 0; s < 8; ++s) {
        const f16* hcur = (s & 1) ? h_b : h_a;
        f16*       hnxt = (s & 1) ? h_a : h_b;
        mgemm<<<dim3(391, 2), 256, 0, stream>>>(hcur, 256, WgT + (size_t)s * 65536, 256,
                                                m, 256, (const float*)nullptr,
                                                N_NODES, 256, 256);
        aggregate<<<12500, 256, 0, stream>>>(m, row_off, csr, agg);
        gemm_gates<<<dim3(391, 8), 256, 0, stream>>>(agg, hcur, Bb, hnxt, brz, bin, bhn, N_NODES);
    }

    // after s=7, result is in h_a
    final_kernel<<<12500, 256, 0, stream>>>(h_a, wlin, blin, d_out, flag);
}

// Round 6
// 1306.127 us; speedup vs baseline: 5.0973x; 1.4042x over previous
//
#include <hip/hip_runtime.h>

typedef _Float16 f16;
typedef unsigned short u16;
typedef unsigned int u32;
typedef _Float16 f16x4 __attribute__((ext_vector_type(4)));
typedef _Float16 f16x8 __attribute__((ext_vector_type(8)));
typedef float    floatx4 __attribute__((ext_vector_type(4)));

#define N_NODES 50000
#define N_EDGES 300000
#define ANNOT   200
#define KXP     224     // x K padded to multiple of 32
#define HID     256

// Device-pass-only intrinsics (undeclared in hipcc's host pass).
__device__ __forceinline__ floatx4 mfma_16x16x32_f16(f16x8 a, f16x8 b, floatx4 c) {
#if defined(__HIP_DEVICE_COMPILE__)
    return __builtin_amdgcn_mfma_f32_16x16x32_f16(a, b, c, 0, 0, 0);
#else
    return c;
#endif
}
__device__ __forceinline__ void gload_lds16(const f16* g, f16* l) {
#if defined(__HIP_DEVICE_COMPILE__)
    __builtin_amdgcn_global_load_lds((const __attribute__((address_space(1))) void*)g,
                                     (__attribute__((address_space(3))) void*)l, 16, 0, 0);
#else
    (void)g; (void)l;
#endif
}

__device__ __forceinline__ float sigm(float x) { return 1.0f / (1.0f + __expf(-x)); }
__device__ __forceinline__ float tanh_fast(float x) { return 1.0f - 2.0f / (1.0f + __expf(2.0f * x)); }

// ---------- dtype helpers ----------
__device__ __forceinline__ float bf_bits_to_f32(u16 u) {
    union { u32 i; float f; } v; v.i = ((u32)u) << 16; return v.f;
}
__device__ __forceinline__ u16 f32_to_bf_bits(float f) {
    union { float f; u32 i; } v; v.f = f;
    u32 b = v.i;
    b += 0x7FFFu + ((b >> 16) & 1u);
    return (u16)(b >> 16);
}
// flag: 0 = inputs are bf16 (u16), 1 = inputs are float32
__device__ __forceinline__ float load_in(const void* p, long i, int flag) {
    if (flag) return ((const float*)p)[i];
    return bf_bits_to_f32(((const u16*)p)[i]);
}

// ---------- dtype probe ----------
__global__ void probe_dtype(const u32* __restrict__ xw, int* __restrict__ flag) {
    __shared__ int cnt;
    if (threadIdx.x == 0) cnt = 0;
    __syncthreads();
    int c = 0;
    for (int i = threadIdx.x; i < 256; i += 64) {
        u32 lo = xw[i] & 0xFFFFu;
        u32 e = (lo >> 7) & 0xFFu;
        if (e >= 105u && e <= 140u) c++;
    }
    atomicAdd(&cnt, c);
    __syncthreads();
    if (threadIdx.x == 0) flag[0] = (cnt > 128) ? 0 : 1;
}

// ---------- prep ----------
__global__ void cvt_f16(const void* __restrict__ in, f16* __restrict__ out, int n,
                        const int* __restrict__ flagp) {
    const int flag = *flagp;
    const int i = blockIdx.x * 256 + threadIdx.x;
    if (i < n) out[i] = (f16)load_in(in, i, flag);
}

// WrT[n][k] (256 x KXP), from W_reduce [256,200] row-major
__global__ void build_wrT(const void* __restrict__ Wre, f16* __restrict__ WrT,
                          const int* __restrict__ flagp) {
    const int flag = *flagp;
    const int i = blockIdx.x * 256 + threadIdx.x;
    if (i >= 256 * KXP) return;
    const int n = i / KXP, k = i - n * KXP;
    WrT[i] = (k < ANNOT) ? (f16)load_in(Wre, (long)n * ANNOT + k, flag) : (f16)0.0f;
}

// Bb8[s][1024][512]; row = chblk*128 + g*32 + c, channel ch = chblk*32+c.
// k<256 half multiplies hsum (uses Wc = Wih_sub @ Wg^T); k>=256 multiplies h (Whh).
// g=0 r, g=1 z, g=2 i_n (Wc only), g=3 h_n (Whh only)
__global__ void build_bb8(const f16* __restrict__ Wc, const void* __restrict__ Whh,
                          f16* __restrict__ Bb, const int* __restrict__ flagp) {
    const int flag = *flagp;
    const int i = blockIdx.x * 256 + threadIdx.x;   // 8 * 1024 * 512
    const int s = i >> 19;
    const int rem = i & 524287;
    const int row = rem >> 9;
    const int k = rem & 511;
    const int chblk = row >> 7;
    const int r = row & 127;
    const int g = r >> 5;
    const int c = r & 31;
    const int ch = chblk * 32 + c;
    f16 v = (f16)0.0f;
    if (g == 0) {
        v = (k < 256) ? Wc[(long)ch * 2048 + s * 256 + k]
                      : (f16)load_in(Whh, (long)ch * 256 + (k - 256), flag);
    } else if (g == 1) {
        v = (k < 256) ? Wc[(long)(256 + ch) * 2048 + s * 256 + k]
                      : (f16)load_in(Whh, (long)(256 + ch) * 256 + (k - 256), flag);
    } else if (g == 2) {
        if (k < 256) v = Wc[(long)(512 + ch) * 2048 + s * 256 + k];
    } else {
        if (k >= 256) v = (f16)load_in(Whh, (long)(512 + ch) * 256 + (k - 256), flag);
    }
    Bb[i] = v;
}

// small fp32 params: brz[512]=b_ih+b_hh, bin[256], bhn[256], br0[256], wlin[512], blin[2]
__global__ void build_small(const void* b_ih, const void* b_hh, const void* b_red,
                            const void* W_lin, const void* b_lin,
                            float* __restrict__ sp, const int* __restrict__ flagp) {
    const int flag = *flagp;
    const int i = blockIdx.x * 256 + threadIdx.x;
    if (i < 512) {
        sp[i] = load_in(b_ih, i, flag) + load_in(b_hh, i, flag);
    } else if (i < 768) {
        sp[i] = load_in(b_ih, 512 + (i - 512), flag);
    } else if (i < 1024) {
        sp[i] = load_in(b_hh, 512 + (i - 768), flag);
    } else if (i < 1280) {
        sp[i] = load_in(b_red, i - 1024, flag);
    } else if (i < 1792) {
        sp[i] = load_in(W_lin, i - 1280, flag);
    } else if (i < 1794) {
        sp[i] = load_in(b_lin, i - 1792, flag);
    }
}

// x_cvt [N, KXP] f16, zero-padded
__global__ void build_xcvt(const void* __restrict__ x, f16* __restrict__ xc,
                           const int* __restrict__ flagp) {
    const int flag = *flagp;
    const long i = (long)blockIdx.x * 256 + threadIdx.x;
    if (i >= (long)N_NODES * KXP) return;
    const long r = i / KXP;
    const int  k = (int)(i - r * KXP);
    xc[i] = (k < ANNOT) ? (f16)load_in(x, r * ANNOT + k, flag) : (f16)0.0f;
}

// ---------- CSR build ----------
__global__ void zero_i32(int* __restrict__ p, int n) {
    const int i = blockIdx.x * 256 + threadIdx.x;
    if (i < n) p[i] = 0;
}
__global__ void hist_kernel(const int* __restrict__ dst, int* __restrict__ deg, int n) {
    const int e = blockIdx.x * 256 + threadIdx.x;
    if (e < n) atomicAdd(&deg[dst[e]], 1);
}
__global__ void block_sum(const int* __restrict__ deg, int* __restrict__ partial, int n) {
    __shared__ int s[256];
    const int i = blockIdx.x * 256 + threadIdx.x;
    s[threadIdx.x] = (i < n) ? deg[i] : 0;
    __syncthreads();
    for (int off = 128; off > 0; off >>= 1) {
        if (threadIdx.x < off) s[threadIdx.x] += s[threadIdx.x + off];
        __syncthreads();
    }
    if (threadIdx.x == 0) partial[blockIdx.x] = s[0];
}
__global__ void scan_partials(int* __restrict__ partial, int nb, int* __restrict__ total_out) {
    __shared__ int s[256];
    const int t = threadIdx.x;
    s[t] = (t < nb) ? partial[t] : 0;
    __syncthreads();
    for (int off = 1; off < 256; off <<= 1) {
        int v = (t >= off) ? s[t - off] : 0;
        __syncthreads();
        s[t] += v;
        __syncthreads();
    }
    if (t < nb) partial[t] = (t == 0) ? 0 : s[t - 1];
    if (t == 0) *total_out = s[255];
}
__global__ void scan_block(const int* __restrict__ deg, const int* __restrict__ partial,
                           int* __restrict__ row_off, int* __restrict__ cursor, int n) {
    __shared__ int s[256];
    const int t = threadIdx.x;
    const int i = blockIdx.x * 256 + t;
    const int v = (i < n) ? deg[i] : 0;
    s[t] = v;
    __syncthreads();
    for (int off = 1; off < 256; off <<= 1) {
        int u = (t >= off) ? s[t - off] : 0;
        __syncthreads();
        s[t] += u;
        __syncthreads();
    }
    if (i < n) {
        const int v0 = partial[blockIdx.x] + s[t] - v;
        row_off[i] = v0;
        cursor[i]  = v0;
    }
}
__global__ void fill_kernel(const int* __restrict__ src, const int* __restrict__ dst,
                            int* __restrict__ cursor, int* __restrict__ csr, int n) {
    const int e = blockIdx.x * 256 + threadIdx.x;
    if (e < n) {
        const int p = atomicAdd(&cursor[dst[e]], 1);
        csr[p] = src[e];
    }
}

// ---------- MFMA GEMM: C[M,N](f16) = A[M,K](f16) * Bt[N,K]^T + bias ----------
// 128x128 tile, 4 waves, BK=32, async global->LDS staging.
__global__ __launch_bounds__(256) void mgemm(
    const f16* __restrict__ A, int lda,
    const f16* __restrict__ Bt, int ldb,
    f16* __restrict__ C, int ldc,
    const float* __restrict__ bias,
    int M, int N, int K)
{
    __shared__ __attribute__((aligned(16))) f16 As[128 * 32];
    __shared__ __attribute__((aligned(16))) f16 Bs[128 * 32];
    const int tid  = threadIdx.x;
    const int lane = tid & 63;
    const int wave = tid >> 6;
    const int bm = blockIdx.x * 128;
    const int bn = blockIdx.y * 128;
    const int wm = (wave >> 1) * 64;
    const int wn = (wave & 1) * 64;
    const int quad = lane >> 4;
    const int l16  = lane & 15;

    floatx4 acc[4][4];
#pragma unroll
    for (int i = 0; i < 4; ++i)
#pragma unroll
        for (int j = 0; j < 4; ++j) acc[i][j] = (floatx4)(0.0f);

    for (int k0 = 0; k0 < K; k0 += 32) {
        __syncthreads();
#pragma unroll
        for (int it = 0; it < 2; ++it) {
            const int ci  = it * 256 + tid;   // 0..511
            const int row = ci >> 2;
            const int cg  = ci & 3;
            int ga = bm + row; if (ga > M - 1) ga = M - 1;
            gload_lds16(A + (long)ga * lda + k0 + cg * 8, As + ci * 8);
            gload_lds16(Bt + (long)(bn + row) * ldb + k0 + cg * 8, Bs + ci * 8);
        }
        __syncthreads();

        f16x8 af[4], bfv[4];
#pragma unroll
        for (int i = 0; i < 4; ++i) {
            af[i]  = *(const f16x8*)(As + (wm + i * 16 + l16) * 32 + quad * 8);
            bfv[i] = *(const f16x8*)(Bs + (wn + i * 16 + l16) * 32 + quad * 8);
        }
#pragma unroll
        for (int i = 0; i < 4; ++i)
#pragma unroll
            for (int j = 0; j < 4; ++j)
                acc[i][j] = mfma_16x16x32_f16(af[i], bfv[j], acc[i][j]);
    }

#pragma unroll
    for (int i = 0; i < 4; ++i) {
        const int r0 = bm + wm + i * 16 + quad * 4;
#pragma unroll
        for (int j = 0; j < 4; ++j) {
            const int col = bn + wn + j * 16 + l16;
            const float bv = bias ? bias[col] : 0.0f;
#pragma unroll
            for (int v = 0; v < 4; ++v) {
                const int r = r0 + v;
                if (r < M) C[(long)r * ldc + col] = (f16)(acc[i][j][v] + bv);
            }
        }
    }
}

// ---------- gates GEMM + fused GRU ----------
// A = agh rows [hsum | h] (K=512, contiguous), B = Bb_s[1024][512],
// row = chblk*128 + gate*32 + c. Grid: x = channel block (8), y = row block.
__global__ __launch_bounds__(256) void gemm_gates(
    const f16* __restrict__ agh, const f16* __restrict__ Bb,
    f16* __restrict__ agh_nxt,
    const float* __restrict__ brz, const float* __restrict__ bin,
    const float* __restrict__ bhn, int M)
{
    __shared__ __attribute__((aligned(16))) f16 As[128 * 32];
    __shared__ __attribute__((aligned(16))) f16 Bs[128 * 32];
    const int tid  = threadIdx.x;
    const int lane = tid & 63;
    const int wave = tid >> 6;
    const int bm = blockIdx.y * 128;
    const int by = blockIdx.x;            // channel block (32 ch)
    const int wm  = (wave >> 1) * 64;
    const int chh = (wave & 1) * 16;      // channel half within block
    const int quad = lane >> 4;
    const int l16  = lane & 15;

    floatx4 acc[4][4];
#pragma unroll
    for (int i = 0; i < 4; ++i)
#pragma unroll
        for (int j = 0; j < 4; ++j) acc[i][j] = (floatx4)(0.0f);

    for (int k0 = 0; k0 < 512; k0 += 32) {
        __syncthreads();
#pragma unroll
        for (int it = 0; it < 2; ++it) {
            const int ci  = it * 256 + tid;
            const int row = ci >> 2;
            const int cg  = ci & 3;
            int ga = bm + row; if (ga > M - 1) ga = M - 1;
            gload_lds16(agh + (long)ga * 512 + k0 + cg * 8, As + ci * 8);
            gload_lds16(Bb + (long)(by * 128 + row) * 512 + k0 + cg * 8, Bs + ci * 8);
        }
        __syncthreads();

        f16x8 af[4], bfv[4];
#pragma unroll
        for (int i = 0; i < 4; ++i) {
            af[i]  = *(const f16x8*)(As + (wm + i * 16 + l16) * 32 + quad * 8);
            bfv[i] = *(const f16x8*)(Bs + (i * 32 + chh + l16) * 32 + quad * 8);
        }
#pragma unroll
        for (int i = 0; i < 4; ++i)
#pragma unroll
            for (int j = 0; j < 4; ++j)
                acc[i][j] = mfma_16x16x32_f16(af[i], bfv[j], acc[i][j]);
    }

    // epilogue: lane owns channel ch; acc[i][g][v] = gate g preact at row r0+v
    const int ch = by * 32 + chh + l16;
    const float b_r  = brz[ch];
    const float b_z  = brz[256 + ch];
    const float b_in = bin[ch];
    const float b_hn = bhn[ch];
#pragma unroll
    for (int i = 0; i < 4; ++i) {
        const int r0 = bm + wm + i * 16 + quad * 4;
#pragma unroll
        for (int v = 0; v < 4; ++v) {
            const int r = r0 + v;
            if (r < M) {
                const float rg = sigm(acc[i][0][v] + b_r);
                const float zg = sigm(acc[i][1][v] + b_z);
                const float nn = tanh_fast(acc[i][2][v] + b_in + rg * (acc[i][3][v] + b_hn));
                const float ho = (float)agh[(long)r * 512 + 256 + ch];
                agh_nxt[(long)r * 512 + 256 + ch] = (f16)((1.0f - zg) * nn + zg * ho);
            }
        }
    }
}

// ---------- aggregate: agh[v][0:256] = sum_{e: dst=v} agh[src[e]][256:512] ----------
__global__ __launch_bounds__(256) void aggregate(
    f16* __restrict__ agh, const int* __restrict__ row_off, const int* __restrict__ csr)
{
    const int node = blockIdx.x * 4 + (threadIdx.x >> 6);
    const int lane = threadIdx.x & 63;
    if (node >= N_NODES) return;
    const int e0 = row_off[node], e1 = row_off[node + 1];
    float a0 = 0.0f, a1 = 0.0f, a2 = 0.0f, a3 = 0.0f;
    for (int e = e0; e < e1; ++e) {
        const int s = csr[e];
        const f16x4 v = *(const f16x4*)(agh + (long)s * 512 + 256 + lane * 4);
        a0 += (float)v[0]; a1 += (float)v[1]; a2 += (float)v[2]; a3 += (float)v[3];
    }
    f16x4 o;
    o[0] = (f16)a0; o[1] = (f16)a1; o[2] = (f16)a2; o[3] = (f16)a3;
    *(f16x4*)(agh + (long)node * 512 + lane * 4) = o;
}

// ---------- final head ----------
__global__ __launch_bounds__(256) void final_kernel(
    const f16* __restrict__ h, const float* __restrict__ wlin,
    const float* __restrict__ blin, void* __restrict__ out,
    const int* __restrict__ flagp)
{
    const int flag = *flagp;
    const int node = blockIdx.x * 4 + (threadIdx.x >> 6);
    const int lane = threadIdx.x & 63;
    if (node >= N_NODES) return;
    const f16* hp = h + (long)node * 512;
    float a0 = 0.0f, a1 = 0.0f;
#pragma unroll
    for (int u = 0; u < 4; ++u) {
        const int c = lane * 4 + u;
        float hv = (float)hp[c];
        hv = hv > 0.0f ? hv : 0.0f;
        a0 += hv * wlin[c];
        a1 += hv * wlin[256 + c];
    }
#pragma unroll
    for (int off = 32; off > 0; off >>= 1) {
        a0 += __shfl_down(a0, off);
        a1 += __shfl_down(a1, off);
    }
    if (lane == 0) {
        a0 += blin[0];
        a1 += blin[1];
        const float mx  = fmaxf(a0, a1);
        const float lse = mx + logf(expf(a0 - mx) + expf(a1 - mx));
        const float o0 = a0 - lse, o1 = a1 - lse;
        if (flag) {
            ((float*)out)[(long)node * 2]     = o0;
            ((float*)out)[(long)node * 2 + 1] = o1;
        } else {
            ((u16*)out)[(long)node * 2]     = f32_to_bf_bits(o0);
            ((u16*)out)[(long)node * 2 + 1] = f32_to_bf_bits(o1);
        }
    }
}

extern "C" void kernel_launch(void* const* d_in, const int* in_sizes, int n_in,
                              void* d_out, int out_size, void* d_ws, size_t ws_size,
                              hipStream_t stream)
{
    (void)in_sizes; (void)n_in; (void)out_size; (void)ws_size;
    const void* x        = d_in[0];
    const int*  ei       = (const int*)d_in[1];
    const void* W_reduce = d_in[3];
    const void* b_reduce = d_in[4];
    const void* W_ggc    = d_in[5];
    const void* W_ih     = d_in[6];
    const void* W_hh     = d_in[7];
    const void* b_ih     = d_in[8];
    const void* b_hh     = d_in[9];
    const void* W_lin    = d_in[10];
    const void* b_lin    = d_in[11];
    const int* src = ei;
    const int* dst = ei + N_EDGES;

    char* w = (char*)d_ws;
    auto carve = [&](size_t bytes) -> char* {
        char* p = w;
        w += (bytes + 255) & ~(size_t)255;
        return p;
    };
    // agh layout: [N][512] f16; cols 0..255 = hsum, 256..511 = h
    f16* agh_a = (f16*)carve((size_t)N_NODES * 512 * 2);
    f16* agh_b = (f16*)carve((size_t)N_NODES * 512 * 2);   // union with x_cvt [N,KXP]
    f16* x_cvt = agh_b;   // dead before agh_b's first write (gates s=0)
    f16*   WrT   = (f16*)carve((size_t)256 * KXP * 2);
    f16*   Wih16 = (f16*)carve((size_t)768 * 256 * 2);
    f16*   Wg16  = (f16*)carve((size_t)2048 * 256 * 2);
    f16*   Wc    = (f16*)carve((size_t)768 * 2048 * 2);
    f16*   Bb8   = (f16*)carve((size_t)8 * 1024 * 512 * 2);
    float* sp    = (float*)carve(2048 * 4);
    int*   flag  = (int*)carve(256);
    int* deg     = (int*)carve((size_t)N_NODES * 4);
    int* row_off = (int*)carve((size_t)(N_NODES + 1) * 4);
    int* cursor  = (int*)carve((size_t)N_NODES * 4);
    int* csr     = (int*)carve((size_t)N_EDGES * 4);
    int* partial = (int*)carve(256 * 4);

    float* brz  = sp;
    float* bin  = sp + 512;
    float* bhn  = sp + 768;
    float* br0  = sp + 1024;
    float* wlin = sp + 1280;
    float* blin = sp + 1792;

    probe_dtype<<<1, 64, 0, stream>>>((const u32*)x, flag);

    cvt_f16<<<(768 * 256 + 255) / 256, 256, 0, stream>>>(W_ih, Wih16, 768 * 256, flag);
    cvt_f16<<<(2048 * 256 + 255) / 256, 256, 0, stream>>>(W_ggc, Wg16, 2048 * 256, flag);
    build_wrT<<<(256 * KXP + 255) / 256, 256, 0, stream>>>(W_reduce, WrT, flag);
    build_small<<<8, 256, 0, stream>>>(b_ih, b_hh, b_reduce, W_lin, b_lin, sp, flag);
    build_xcvt<<<(int)(((long)N_NODES * KXP + 255) / 256), 256, 0, stream>>>(x, x_cvt, flag);

    zero_i32<<<196, 256, 0, stream>>>(deg, N_NODES);
    hist_kernel<<<(N_EDGES + 255) / 256, 256, 0, stream>>>(dst, deg, N_EDGES);
    block_sum<<<196, 256, 0, stream>>>(deg, partial, N_NODES);
    scan_partials<<<1, 256, 0, stream>>>(partial, 196, row_off + N_NODES);
    scan_block<<<196, 256, 0, stream>>>(deg, partial, row_off, cursor, N_NODES);
    fill_kernel<<<(N_EDGES + 255) / 256, 256, 0, stream>>>(src, dst, cursor, csr, N_EDGES);

    // Wc[c][s*256+k] = sum_n Wih[c][n] * Wg_s[k][n]  (one GEMM: M=768, N=2048, K=256)
    mgemm<<<dim3(6, 16), 256, 0, stream>>>(Wih16, 256, Wg16, 256, Wc, 2048,
                                           (const float*)nullptr, 768, 2048, 256);
    build_bb8<<<(8 * 1024 * 512) / 256, 256, 0, stream>>>(Wc, W_hh, Bb8, flag);

    // h0 = x @ W_reduce^T + b_reduce -> agh_a cols 256..511
    mgemm<<<dim3(391, 2), 256, 0, stream>>>(x_cvt, KXP, WrT, KXP, agh_a + 256, 512, br0,
                                            N_NODES, 256, KXP);

    for (int s = 0; s < 8; ++s) {
        f16* cur = (s & 1) ? agh_b : agh_a;
        f16* nxt = (s & 1) ? agh_a : agh_b;
        aggregate<<<12500, 256, 0, stream>>>(cur, row_off, csr);
        gemm_gates<<<dim3(8, 391), 256, 0, stream>>>(cur, Bb8 + (size_t)s * 524288, nxt,
                                                     brz, bin, bhn, N_NODES);
    }

    // after s=7, h is in agh_a cols 256..511
    final_kernel<<<12500, 256, 0, stream>>>(agh_a + 256, wlin, blin, d_out, flag);
}

// Round 7
// 1265.126 us; speedup vs baseline: 5.2625x; 1.0324x over previous
//
#include <hip/hip_runtime.h>

typedef _Float16 f16;
typedef unsigned short u16;
typedef unsigned int u32;
typedef _Float16 f16x4 __attribute__((ext_vector_type(4)));
typedef _Float16 f16x8 __attribute__((ext_vector_type(8)));
typedef float    floatx4 __attribute__((ext_vector_type(4)));

#define N_NODES 50000
#define N_EDGES 300000
#define ANNOT   200
#define KXP     224     // x K padded to multiple of 32
#define HID     256

// Device-pass-only intrinsics (undeclared in hipcc's host pass).
__device__ __forceinline__ floatx4 mfma_16x16x32_f16(f16x8 a, f16x8 b, floatx4 c) {
#if defined(__HIP_DEVICE_COMPILE__)
    return __builtin_amdgcn_mfma_f32_16x16x32_f16(a, b, c, 0, 0, 0);
#else
    return c;
#endif
}
__device__ __forceinline__ void gload_lds16(const f16* g, f16* l) {
#if defined(__HIP_DEVICE_COMPILE__)
    __builtin_amdgcn_global_load_lds((const __attribute__((address_space(1))) void*)g,
                                     (__attribute__((address_space(3))) void*)l, 16, 0, 0);
#else
    (void)g; (void)l;
#endif
}

__device__ __forceinline__ float sigm(float x) { return 1.0f / (1.0f + __expf(-x)); }
__device__ __forceinline__ float tanh_fast(float x) { return 1.0f - 2.0f / (1.0f + __expf(2.0f * x)); }

// ---------- dtype helpers ----------
__device__ __forceinline__ float bf_bits_to_f32(u16 u) {
    union { u32 i; float f; } v; v.i = ((u32)u) << 16; return v.f;
}
__device__ __forceinline__ u16 f32_to_bf_bits(float f) {
    union { float f; u32 i; } v; v.f = f;
    u32 b = v.i;
    b += 0x7FFFu + ((b >> 16) & 1u);
    return (u16)(b >> 16);
}
// flag: 0 = inputs are bf16 (u16), 1 = inputs are float32
__device__ __forceinline__ float load_in(const void* p, long i, int flag) {
    if (flag) return ((const float*)p)[i];
    return bf_bits_to_f32(((const u16*)p)[i]);
}

// ---------- dtype probe ----------
__global__ void probe_dtype(const u32* __restrict__ xw, int* __restrict__ flag) {
    __shared__ int cnt;
    if (threadIdx.x == 0) cnt = 0;
    __syncthreads();
    int c = 0;
    for (int i = threadIdx.x; i < 256; i += 64) {
        u32 lo = xw[i] & 0xFFFFu;
        u32 e = (lo >> 7) & 0xFFu;
        if (e >= 105u && e <= 140u) c++;
    }
    atomicAdd(&cnt, c);
    __syncthreads();
    if (threadIdx.x == 0) flag[0] = (cnt > 128) ? 0 : 1;
}

// ---------- prep ----------
__global__ void cvt_f16(const void* __restrict__ in, f16* __restrict__ out, int n,
                        const int* __restrict__ flagp) {
    const int flag = *flagp;
    const int i = blockIdx.x * 256 + threadIdx.x;
    if (i < n) out[i] = (f16)load_in(in, i, flag);
}

// WrT[n][k] (256 x KXP), from W_reduce [256,200] row-major
__global__ void build_wrT(const void* __restrict__ Wre, f16* __restrict__ WrT,
                          const int* __restrict__ flagp) {
    const int flag = *flagp;
    const int i = blockIdx.x * 256 + threadIdx.x;
    if (i >= 256 * KXP) return;
    const int n = i / KXP, k = i - n * KXP;
    WrT[i] = (k < ANNOT) ? (f16)load_in(Wre, (long)n * ANNOT + k, flag) : (f16)0.0f;
}

// Bb8[s][1024][512]; row = chblk*128 + g*32 + c, channel ch = chblk*32+c.
// k<256 half multiplies hsum (uses Wc = Wih_sub @ Wg^T); k>=256 multiplies h (Whh).
// g=0 r, g=1 z, g=2 i_n (Wc only), g=3 h_n (Whh only)
__global__ void build_bb8(const f16* __restrict__ Wc, const void* __restrict__ Whh,
                          f16* __restrict__ Bb, const int* __restrict__ flagp) {
    const int flag = *flagp;
    const int i = blockIdx.x * 256 + threadIdx.x;   // 8 * 1024 * 512
    const int s = i >> 19;
    const int rem = i & 524287;
    const int row = rem >> 9;
    const int k = rem & 511;
    const int chblk = row >> 7;
    const int r = row & 127;
    const int g = r >> 5;
    const int c = r & 31;
    const int ch = chblk * 32 + c;
    f16 v = (f16)0.0f;
    if (g == 0) {
        v = (k < 256) ? Wc[(long)ch * 2048 + s * 256 + k]
                      : (f16)load_in(Whh, (long)ch * 256 + (k - 256), flag);
    } else if (g == 1) {
        v = (k < 256) ? Wc[(long)(256 + ch) * 2048 + s * 256 + k]
                      : (f16)load_in(Whh, (long)(256 + ch) * 256 + (k - 256), flag);
    } else if (g == 2) {
        if (k < 256) v = Wc[(long)(512 + ch) * 2048 + s * 256 + k];
    } else {
        if (k >= 256) v = (f16)load_in(Whh, (long)(512 + ch) * 256 + (k - 256), flag);
    }
    Bb[i] = v;
}

// small fp32 params: brz[512]=b_ih+b_hh, bin[256], bhn[256], br0[256], wlin[512], blin[2]
__global__ void build_small(const void* b_ih, const void* b_hh, const void* b_red,
                            const void* W_lin, const void* b_lin,
                            float* __restrict__ sp, const int* __restrict__ flagp) {
    const int flag = *flagp;
    const int i = blockIdx.x * 256 + threadIdx.x;
    if (i < 512) {
        sp[i] = load_in(b_ih, i, flag) + load_in(b_hh, i, flag);
    } else if (i < 768) {
        sp[i] = load_in(b_ih, 512 + (i - 512), flag);
    } else if (i < 1024) {
        sp[i] = load_in(b_hh, 512 + (i - 768), flag);
    } else if (i < 1280) {
        sp[i] = load_in(b_red, i - 1024, flag);
    } else if (i < 1792) {
        sp[i] = load_in(W_lin, i - 1280, flag);
    } else if (i < 1794) {
        sp[i] = load_in(b_lin, i - 1792, flag);
    }
}

// x_cvt [N, KXP] f16, zero-padded
__global__ void build_xcvt(const void* __restrict__ x, f16* __restrict__ xc,
                           const int* __restrict__ flagp) {
    const int flag = *flagp;
    const long i = (long)blockIdx.x * 256 + threadIdx.x;
    if (i >= (long)N_NODES * KXP) return;
    const long r = i / KXP;
    const int  k = (int)(i - r * KXP);
    xc[i] = (k < ANNOT) ? (f16)load_in(x, r * ANNOT + k, flag) : (f16)0.0f;
}

// ---------- CSR build ----------
__global__ void zero_i32(int* __restrict__ p, int n) {
    const int i = blockIdx.x * 256 + threadIdx.x;
    if (i < n) p[i] = 0;
}
__global__ void hist_kernel(const int* __restrict__ dst, int* __restrict__ deg, int n) {
    const int e = blockIdx.x * 256 + threadIdx.x;
    if (e < n) atomicAdd(&deg[dst[e]], 1);
}
__global__ void block_sum(const int* __restrict__ deg, int* __restrict__ partial, int n) {
    __shared__ int s[256];
    const int i = blockIdx.x * 256 + threadIdx.x;
    s[threadIdx.x] = (i < n) ? deg[i] : 0;
    __syncthreads();
    for (int off = 128; off > 0; off >>= 1) {
        if (threadIdx.x < off) s[threadIdx.x] += s[threadIdx.x + off];
        __syncthreads();
    }
    if (threadIdx.x == 0) partial[blockIdx.x] = s[0];
}
__global__ void scan_partials(int* __restrict__ partial, int nb, int* __restrict__ total_out) {
    __shared__ int s[256];
    const int t = threadIdx.x;
    s[t] = (t < nb) ? partial[t] : 0;
    __syncthreads();
    for (int off = 1; off < 256; off <<= 1) {
        int v = (t >= off) ? s[t - off] : 0;
        __syncthreads();
        s[t] += v;
        __syncthreads();
    }
    if (t < nb) partial[t] = (t == 0) ? 0 : s[t - 1];
    if (t == 0) *total_out = s[255];
}
__global__ void scan_block(const int* __restrict__ deg, const int* __restrict__ partial,
                           int* __restrict__ row_off, int* __restrict__ cursor, int n) {
    __shared__ int s[256];
    const int t = threadIdx.x;
    const int i = blockIdx.x * 256 + t;
    const int v = (i < n) ? deg[i] : 0;
    s[t] = v;
    __syncthreads();
    for (int off = 1; off < 256; off <<= 1) {
        int u = (t >= off) ? s[t - off] : 0;
        __syncthreads();
        s[t] += u;
        __syncthreads();
    }
    if (i < n) {
        const int v0 = partial[blockIdx.x] + s[t] - v;
        row_off[i] = v0;
        cursor[i]  = v0;
    }
}
__global__ void fill_kernel(const int* __restrict__ src, const int* __restrict__ dst,
                            int* __restrict__ cursor, int* __restrict__ csr, int n) {
    const int e = blockIdx.x * 256 + threadIdx.x;
    if (e < n) {
        const int p = atomicAdd(&cursor[dst[e]], 1);
        csr[p] = src[e];
    }
}

// ---------- MFMA GEMM: C[M,N](f16) = A[M,K](f16) * Bt[N,K]^T + bias ----------
// 128x128 tile, 4 waves, BK=32, async global->LDS staging.
__global__ __launch_bounds__(256) void mgemm(
    const f16* __restrict__ A, int lda,
    const f16* __restrict__ Bt, int ldb,
    f16* __restrict__ C, int ldc,
    const float* __restrict__ bias,
    int M, int N, int K)
{
    __shared__ __attribute__((aligned(16))) f16 As[128 * 32];
    __shared__ __attribute__((aligned(16))) f16 Bs[128 * 32];
    const int tid  = threadIdx.x;
    const int lane = tid & 63;
    const int wave = tid >> 6;
    const int bm = blockIdx.x * 128;
    const int bn = blockIdx.y * 128;
    const int wm = (wave >> 1) * 64;
    const int wn = (wave & 1) * 64;
    const int quad = lane >> 4;
    const int l16  = lane & 15;

    floatx4 acc[4][4];
#pragma unroll
    for (int i = 0; i < 4; ++i)
#pragma unroll
        for (int j = 0; j < 4; ++j) acc[i][j] = (floatx4)(0.0f);

    for (int k0 = 0; k0 < K; k0 += 32) {
        __syncthreads();
#pragma unroll
        for (int it = 0; it < 2; ++it) {
            const int ci  = it * 256 + tid;   // 0..511
            const int row = ci >> 2;
            const int cg  = ci & 3;
            int ga = bm + row; if (ga > M - 1) ga = M - 1;
            gload_lds16(A + (long)ga * lda + k0 + cg * 8, As + ci * 8);
            gload_lds16(Bt + (long)(bn + row) * ldb + k0 + cg * 8, Bs + ci * 8);
        }
        __syncthreads();

        f16x8 af[4], bfv[4];
#pragma unroll
        for (int i = 0; i < 4; ++i) {
            af[i]  = *(const f16x8*)(As + (wm + i * 16 + l16) * 32 + quad * 8);
            bfv[i] = *(const f16x8*)(Bs + (wn + i * 16 + l16) * 32 + quad * 8);
        }
#pragma unroll
        for (int i = 0; i < 4; ++i)
#pragma unroll
            for (int j = 0; j < 4; ++j)
                acc[i][j] = mfma_16x16x32_f16(af[i], bfv[j], acc[i][j]);
    }

#pragma unroll
    for (int i = 0; i < 4; ++i) {
        const int r0 = bm + wm + i * 16 + quad * 4;
#pragma unroll
        for (int j = 0; j < 4; ++j) {
            const int col = bn + wn + j * 16 + l16;
            const float bv = bias ? bias[col] : 0.0f;
#pragma unroll
            for (int v = 0; v < 4; ++v) {
                const int r = r0 + v;
                if (r < M) C[(long)r * ldc + col] = (f16)(acc[i][j][v] + bv);
            }
        }
    }
}

// ---------- gates GEMM + fused GRU ----------
// A = agh rows [hsum | h] (K=512), B = Bb_s[1024][512], row = chblk*128+gate*32+c.
// 1-D grid with XCD swizzle: all 8 channel-blocks of a row-block land on the same
// XCD (blockIdx % 8 == rb % 8) so the A-tile is fetched into that XCD's L2 once.
__global__ __launch_bounds__(256) void gemm_gates(
    const f16* __restrict__ agh, const f16* __restrict__ Bb,
    f16* __restrict__ agh_nxt,
    const float* __restrict__ brz, const float* __restrict__ bin,
    const float* __restrict__ bhn, int M)
{
    const int lin = blockIdx.x;
    const int within = lin & 63;
    const int rb = (lin >> 6) * 8 + (within & 7);   // row block
    const int cb = within >> 3;                     // channel block 0..7
    if (rb * 128 >= M) return;

    __shared__ __attribute__((aligned(16))) f16 As[128 * 32];
    __shared__ __attribute__((aligned(16))) f16 Bs[128 * 32];
    const int tid  = threadIdx.x;
    const int lane = tid & 63;
    const int wave = tid >> 6;
    const int bm = rb * 128;
    const int wm  = (wave >> 1) * 64;
    const int chh = (wave & 1) * 16;      // channel half within block
    const int quad = lane >> 4;
    const int l16  = lane & 15;
    const int k_cap = 256 + cb * 32;      // k-slice holding this block's h channels

    floatx4 acc[4][4];
#pragma unroll
    for (int i = 0; i < 4; ++i)
#pragma unroll
        for (int j = 0; j < 4; ++j) acc[i][j] = (floatx4)(0.0f);
    f16 h_frag[4][4] = {};

    for (int k0 = 0; k0 < 512; k0 += 32) {
        __syncthreads();
#pragma unroll
        for (int it = 0; it < 2; ++it) {
            const int ci  = it * 256 + tid;
            const int row = ci >> 2;
            const int cg  = ci & 3;
            int ga = bm + row; if (ga > M - 1) ga = M - 1;
            gload_lds16(agh + (long)ga * 512 + k0 + cg * 8, As + ci * 8);
            gload_lds16(Bb + (long)(cb * 128 + row) * 512 + k0 + cg * 8, Bs + ci * 8);
        }
        __syncthreads();

        if (k0 == k_cap) {   // capture h[r][ch] from the staged A slice
#pragma unroll
            for (int i = 0; i < 4; ++i)
#pragma unroll
                for (int v = 0; v < 4; ++v)
                    h_frag[i][v] = As[(wm + i * 16 + quad * 4 + v) * 32 + chh + l16];
        }

        f16x8 af[4], bfv[4];
#pragma unroll
        for (int i = 0; i < 4; ++i) {
            af[i]  = *(const f16x8*)(As + (wm + i * 16 + l16) * 32 + quad * 8);
            bfv[i] = *(const f16x8*)(Bs + (i * 32 + chh + l16) * 32 + quad * 8);
        }
#pragma unroll
        for (int i = 0; i < 4; ++i)
#pragma unroll
            for (int j = 0; j < 4; ++j)
                acc[i][j] = mfma_16x16x32_f16(af[i], bfv[j], acc[i][j]);
    }

    // epilogue: lane owns channel ch; acc[i][g][v] = gate g preact at row r0+v
    const int ch = cb * 32 + chh + l16;
    const float b_r  = brz[ch];
    const float b_z  = brz[256 + ch];
    const float b_in = bin[ch];
    const float b_hn = bhn[ch];
#pragma unroll
    for (int i = 0; i < 4; ++i) {
        const int r0 = bm + wm + i * 16 + quad * 4;
#pragma unroll
        for (int v = 0; v < 4; ++v) {
            const int r = r0 + v;
            if (r < M) {
                const float rg = sigm(acc[i][0][v] + b_r);
                const float zg = sigm(acc[i][1][v] + b_z);
                const float nn = tanh_fast(acc[i][2][v] + b_in + rg * (acc[i][3][v] + b_hn));
                const float ho = (float)h_frag[i][v];
                agh_nxt[(long)r * 512 + 256 + ch] = (f16)((1.0f - zg) * nn + zg * ho);
            }
        }
    }
}

// ---------- aggregate: agh[v][0:256] = sum_{e: dst=v} agh[src[e]][256:512] ----------
// half-wave (32 lanes x f16x8 = 512B row) per node
__global__ __launch_bounds__(256) void aggregate(
    f16* __restrict__ agh, const int* __restrict__ row_off, const int* __restrict__ csr)
{
    const int node = blockIdx.x * 8 + (threadIdx.x >> 5);
    const int lane = threadIdx.x & 31;
    if (node >= N_NODES) return;
    const int e0 = row_off[node], e1 = row_off[node + 1];
    float a[8] = {0.0f, 0.0f, 0.0f, 0.0f, 0.0f, 0.0f, 0.0f, 0.0f};
    for (int e = e0; e < e1; ++e) {
        const int s = csr[e];
        const f16x8 v = *(const f16x8*)(agh + (long)s * 512 + 256 + lane * 8);
#pragma unroll
        for (int u = 0; u < 8; ++u) a[u] += (float)v[u];
    }
    f16x8 o;
#pragma unroll
    for (int u = 0; u < 8; ++u) o[u] = (f16)a[u];
    *(f16x8*)(agh + (long)node * 512 + lane * 8) = o;
}

// ---------- final head ----------
__global__ __launch_bounds__(256) void final_kernel(
    const f16* __restrict__ h, const float* __restrict__ wlin,
    const float* __restrict__ blin, void* __restrict__ out,
    const int* __restrict__ flagp)
{
    const int flag = *flagp;
    const int node = blockIdx.x * 4 + (threadIdx.x >> 6);
    const int lane = threadIdx.x & 63;
    if (node >= N_NODES) return;
    const f16* hp = h + (long)node * 512;
    float a0 = 0.0f, a1 = 0.0f;
#pragma unroll
    for (int u = 0; u < 4; ++u) {
        const int c = lane * 4 + u;
        float hv = (float)hp[c];
        hv = hv > 0.0f ? hv : 0.0f;
        a0 += hv * wlin[c];
        a1 += hv * wlin[256 + c];
    }
#pragma unroll
    for (int off = 32; off > 0; off >>= 1) {
        a0 += __shfl_down(a0, off);
        a1 += __shfl_down(a1, off);
    }
    if (lane == 0) {
        a0 += blin[0];
        a1 += blin[1];
        const float mx  = fmaxf(a0, a1);
        const float lse = mx + logf(expf(a0 - mx) + expf(a1 - mx));
        const float o0 = a0 - lse, o1 = a1 - lse;
        if (flag) {
            ((float*)out)[(long)node * 2]     = o0;
            ((float*)out)[(long)node * 2 + 1] = o1;
        } else {
            ((u16*)out)[(long)node * 2]     = f32_to_bf_bits(o0);
            ((u16*)out)[(long)node * 2 + 1] = f32_to_bf_bits(o1);
        }
    }
}

extern "C" void kernel_launch(void* const* d_in, const int* in_sizes, int n_in,
                              void* d_out, int out_size, void* d_ws, size_t ws_size,
                              hipStream_t stream)
{
    (void)in_sizes; (void)n_in; (void)out_size; (void)ws_size;
    const void* x        = d_in[0];
    const int*  ei       = (const int*)d_in[1];
    const void* W_reduce = d_in[3];
    const void* b_reduce = d_in[4];
    const void* W_ggc    = d_in[5];
    const void* W_ih     = d_in[6];
    const void* W_hh     = d_in[7];
    const void* b_ih     = d_in[8];
    const void* b_hh     = d_in[9];
    const void* W_lin    = d_in[10];
    const void* b_lin    = d_in[11];
    const int* src = ei;
    const int* dst = ei + N_EDGES;

    char* w = (char*)d_ws;
    auto carve = [&](size_t bytes) -> char* {
        char* p = w;
        w += (bytes + 255) & ~(size_t)255;
        return p;
    };
    // agh layout: [N][512] f16; cols 0..255 = hsum, 256..511 = h
    f16* agh_a = (f16*)carve((size_t)N_NODES * 512 * 2);
    f16* agh_b = (f16*)carve((size_t)N_NODES * 512 * 2);   // union with x_cvt [N,KXP]
    f16* x_cvt = agh_b;   // dead before agh_b's first write (gates s=0)
    f16*   WrT   = (f16*)carve((size_t)256 * KXP * 2);
    f16*   Wih16 = (f16*)carve((size_t)768 * 256 * 2);
    f16*   Wg16  = (f16*)carve((size_t)2048 * 256 * 2);
    f16*   Wc    = (f16*)carve((size_t)768 * 2048 * 2);
    f16*   Bb8   = (f16*)carve((size_t)8 * 1024 * 512 * 2);
    float* sp    = (float*)carve(2048 * 4);
    int*   flag  = (int*)carve(256);
    int* deg     = (int*)carve((size_t)N_NODES * 4);
    int* row_off = (int*)carve((size_t)(N_NODES + 1) * 4);
    int* cursor  = (int*)carve((size_t)N_NODES * 4);
    int* csr     = (int*)carve((size_t)N_EDGES * 4);
    int* partial = (int*)carve(256 * 4);

    float* brz  = sp;
    float* bin  = sp + 512;
    float* bhn  = sp + 768;
    float* br0  = sp + 1024;
    float* wlin = sp + 1280;
    float* blin = sp + 1792;

    probe_dtype<<<1, 64, 0, stream>>>((const u32*)x, flag);

    cvt_f16<<<(768 * 256 + 255) / 256, 256, 0, stream>>>(W_ih, Wih16, 768 * 256, flag);
    cvt_f16<<<(2048 * 256 + 255) / 256, 256, 0, stream>>>(W_ggc, Wg16, 2048 * 256, flag);
    build_wrT<<<(256 * KXP + 255) / 256, 256, 0, stream>>>(W_reduce, WrT, flag);
    build_small<<<8, 256, 0, stream>>>(b_ih, b_hh, b_reduce, W_lin, b_lin, sp, flag);
    build_xcvt<<<(int)(((long)N_NODES * KXP + 255) / 256), 256, 0, stream>>>(x, x_cvt, flag);

    zero_i32<<<196, 256, 0, stream>>>(deg, N_NODES);
    hist_kernel<<<(N_EDGES + 255) / 256, 256, 0, stream>>>(dst, deg, N_EDGES);
    block_sum<<<196, 256, 0, stream>>>(deg, partial, N_NODES);
    scan_partials<<<1, 256, 0, stream>>>(partial, 196, row_off + N_NODES);
    scan_block<<<196, 256, 0, stream>>>(deg, partial, row_off, cursor, N_NODES);
    fill_kernel<<<(N_EDGES + 255) / 256, 256, 0, stream>>>(src, dst, cursor, csr, N_EDGES);

    // Wc[c][s*256+k] = sum_n Wih[c][n] * Wg_s[k][n]  (one GEMM: M=768, N=2048, K=256)
    mgemm<<<dim3(6, 16), 256, 0, stream>>>(Wih16, 256, Wg16, 256, Wc, 2048,
                                           (const float*)nullptr, 768, 2048, 256);
    build_bb8<<<(8 * 1024 * 512) / 256, 256, 0, stream>>>(Wc, W_hh, Bb8, flag);

    // h0 = x @ W_reduce^T + b_reduce -> agh_a cols 256..511
    mgemm<<<dim3(391, 2), 256, 0, stream>>>(x_cvt, KXP, WrT, KXP, agh_a + 256, 512, br0,
                                            N_NODES, 256, KXP);

    for (int s = 0; s < 8; ++s) {
        f16* cur = (s & 1) ? agh_b : agh_a;
        f16* nxt = (s & 1) ? agh_a : agh_b;
        aggregate<<<6250, 256, 0, stream>>>(cur, row_off, csr);
        gemm_gates<<<49 * 64, 256, 0, stream>>>(cur, Bb8 + (size_t)s * 524288, nxt,
                                                brz, bin, bhn, N_NODES);
    }

    // after s=7, h is in agh_a cols 256..511
    final_kernel<<<12500, 256, 0, stream>>>(agh_a + 256, wlin, blin, d_out, flag);
}

// Round 8
// 1156.734 us; speedup vs baseline: 5.7556x; 1.0937x over previous
//
#include <hip/hip_runtime.h>

typedef _Float16 f16;
typedef unsigned short u16;
typedef unsigned int u32;
typedef _Float16 f16x4 __attribute__((ext_vector_type(4)));
typedef _Float16 f16x8 __attribute__((ext_vector_type(8)));
typedef float    floatx4 __attribute__((ext_vector_type(4)));

#define N_NODES 50000
#define N_EDGES 300000
#define ANNOT   200
#define KXP     224     // x K padded to multiple of 32
#define HID     256

// Device-pass-only intrinsics (undeclared in hipcc's host pass).
__device__ __forceinline__ floatx4 mfma_16x16x32_f16(f16x8 a, f16x8 b, floatx4 c) {
#if defined(__HIP_DEVICE_COMPILE__)
    return __builtin_amdgcn_mfma_f32_16x16x32_f16(a, b, c, 0, 0, 0);
#else
    return c;
#endif
}
__device__ __forceinline__ void gload_lds16(const f16* g, f16* l) {
#if defined(__HIP_DEVICE_COMPILE__)
    __builtin_amdgcn_global_load_lds((const __attribute__((address_space(1))) void*)g,
                                     (__attribute__((address_space(3))) void*)l, 16, 0, 0);
#else
    (void)g; (void)l;
#endif
}

__device__ __forceinline__ float sigm(float x) { return 1.0f / (1.0f + __expf(-x)); }
__device__ __forceinline__ float tanh_fast(float x) { return 1.0f - 2.0f / (1.0f + __expf(2.0f * x)); }

// ---------- dtype helpers ----------
__device__ __forceinline__ float bf_bits_to_f32(u16 u) {
    union { u32 i; float f; } v; v.i = ((u32)u) << 16; return v.f;
}
__device__ __forceinline__ u16 f32_to_bf_bits(float f) {
    union { float f; u32 i; } v; v.f = f;
    u32 b = v.i;
    b += 0x7FFFu + ((b >> 16) & 1u);
    return (u16)(b >> 16);
}
// flag: 0 = inputs are bf16 (u16), 1 = inputs are float32
__device__ __forceinline__ float load_in(const void* p, long i, int flag) {
    if (flag) return ((const float*)p)[i];
    return bf_bits_to_f32(((const u16*)p)[i]);
}

// ---------- dtype probe ----------
__global__ void probe_dtype(const u32* __restrict__ xw, int* __restrict__ flag) {
    __shared__ int cnt;
    if (threadIdx.x == 0) cnt = 0;
    __syncthreads();
    int c = 0;
    for (int i = threadIdx.x; i < 256; i += 64) {
        u32 lo = xw[i] & 0xFFFFu;
        u32 e = (lo >> 7) & 0xFFu;
        if (e >= 105u && e <= 140u) c++;
    }
    atomicAdd(&cnt, c);
    __syncthreads();
    if (threadIdx.x == 0) flag[0] = (cnt > 128) ? 0 : 1;
}

// ---------- prep ----------
__global__ void cvt_f16(const void* __restrict__ in, f16* __restrict__ out, int n,
                        const int* __restrict__ flagp) {
    const int flag = *flagp;
    const int i = blockIdx.x * 256 + threadIdx.x;
    if (i < n) out[i] = (f16)load_in(in, i, flag);
}

// WrT[n][k] (256 x KXP), from W_reduce [256,200] row-major
__global__ void build_wrT(const void* __restrict__ Wre, f16* __restrict__ WrT,
                          const int* __restrict__ flagp) {
    const int flag = *flagp;
    const int i = blockIdx.x * 256 + threadIdx.x;
    if (i >= 256 * KXP) return;
    const int n = i / KXP, k = i - n * KXP;
    WrT[i] = (k < ANNOT) ? (f16)load_in(Wre, (long)n * ANNOT + k, flag) : (f16)0.0f;
}

// Bb8[s][1024][512]; row = chblk*128 + g*32 + c, channel ch = chblk*32+c.
// k<256 half multiplies hsum (uses Wc = Wih_sub @ Wg^T); k>=256 multiplies h (Whh).
// g=0 r, g=1 z, g=2 i_n (Wc only), g=3 h_n (Whh only)
__global__ void build_bb8(const f16* __restrict__ Wc, const void* __restrict__ Whh,
                          f16* __restrict__ Bb, const int* __restrict__ flagp) {
    const int flag = *flagp;
    const int i = blockIdx.x * 256 + threadIdx.x;   // 8 * 1024 * 512
    const int s = i >> 19;
    const int rem = i & 524287;
    const int row = rem >> 9;
    const int k = rem & 511;
    const int chblk = row >> 7;
    const int r = row & 127;
    const int g = r >> 5;
    const int c = r & 31;
    const int ch = chblk * 32 + c;
    f16 v = (f16)0.0f;
    if (g == 0) {
        v = (k < 256) ? Wc[(long)ch * 2048 + s * 256 + k]
                      : (f16)load_in(Whh, (long)ch * 256 + (k - 256), flag);
    } else if (g == 1) {
        v = (k < 256) ? Wc[(long)(256 + ch) * 2048 + s * 256 + k]
                      : (f16)load_in(Whh, (long)(256 + ch) * 256 + (k - 256), flag);
    } else if (g == 2) {
        if (k < 256) v = Wc[(long)(512 + ch) * 2048 + s * 256 + k];
    } else {
        if (k >= 256) v = (f16)load_in(Whh, (long)(512 + ch) * 256 + (k - 256), flag);
    }
    Bb[i] = v;
}

// small fp32 params: brz[512]=b_ih+b_hh, bin[256], bhn[256], br0[256], wlin[512], blin[2]
__global__ void build_small(const void* b_ih, const void* b_hh, const void* b_red,
                            const void* W_lin, const void* b_lin,
                            float* __restrict__ sp, const int* __restrict__ flagp) {
    const int flag = *flagp;
    const int i = blockIdx.x * 256 + threadIdx.x;
    if (i < 512) {
        sp[i] = load_in(b_ih, i, flag) + load_in(b_hh, i, flag);
    } else if (i < 768) {
        sp[i] = load_in(b_ih, 512 + (i - 512), flag);
    } else if (i < 1024) {
        sp[i] = load_in(b_hh, 512 + (i - 768), flag);
    } else if (i < 1280) {
        sp[i] = load_in(b_red, i - 1024, flag);
    } else if (i < 1792) {
        sp[i] = load_in(W_lin, i - 1280, flag);
    } else if (i < 1794) {
        sp[i] = load_in(b_lin, i - 1792, flag);
    }
}

// x_cvt [N, KXP] f16, zero-padded
__global__ void build_xcvt(const void* __restrict__ x, f16* __restrict__ xc,
                           const int* __restrict__ flagp) {
    const int flag = *flagp;
    const long i = (long)blockIdx.x * 256 + threadIdx.x;
    if (i >= (long)N_NODES * KXP) return;
    const long r = i / KXP;
    const int  k = (int)(i - r * KXP);
    xc[i] = (k < ANNOT) ? (f16)load_in(x, r * ANNOT + k, flag) : (f16)0.0f;
}

// ---------- CSR build ----------
__global__ void zero_i32(int* __restrict__ p, int n) {
    const int i = blockIdx.x * 256 + threadIdx.x;
    if (i < n) p[i] = 0;
}
__global__ void hist_kernel(const int* __restrict__ dst, int* __restrict__ deg, int n) {
    const int e = blockIdx.x * 256 + threadIdx.x;
    if (e < n) atomicAdd(&deg[dst[e]], 1);
}
__global__ void block_sum(const int* __restrict__ deg, int* __restrict__ partial, int n) {
    __shared__ int s[256];
    const int i = blockIdx.x * 256 + threadIdx.x;
    s[threadIdx.x] = (i < n) ? deg[i] : 0;
    __syncthreads();
    for (int off = 128; off > 0; off >>= 1) {
        if (threadIdx.x < off) s[threadIdx.x] += s[threadIdx.x + off];
        __syncthreads();
    }
    if (threadIdx.x == 0) partial[blockIdx.x] = s[0];
}
__global__ void scan_partials(int* __restrict__ partial, int nb, int* __restrict__ total_out) {
    __shared__ int s[256];
    const int t = threadIdx.x;
    s[t] = (t < nb) ? partial[t] : 0;
    __syncthreads();
    for (int off = 1; off < 256; off <<= 1) {
        int v = (t >= off) ? s[t - off] : 0;
        __syncthreads();
        s[t] += v;
        __syncthreads();
    }
    if (t < nb) partial[t] = (t == 0) ? 0 : s[t - 1];
    if (t == 0) *total_out = s[255];
}
__global__ void scan_block(const int* __restrict__ deg, const int* __restrict__ partial,
                           int* __restrict__ row_off, int* __restrict__ cursor, int n) {
    __shared__ int s[256];
    const int t = threadIdx.x;
    const int i = blockIdx.x * 256 + t;
    const int v = (i < n) ? deg[i] : 0;
    s[t] = v;
    __syncthreads();
    for (int off = 1; off < 256; off <<= 1) {
        int u = (t >= off) ? s[t - off] : 0;
        __syncthreads();
        s[t] += u;
        __syncthreads();
    }
    if (i < n) {
        const int v0 = partial[blockIdx.x] + s[t] - v;
        row_off[i] = v0;
        cursor[i]  = v0;
    }
}
__global__ void fill_kernel(const int* __restrict__ src, const int* __restrict__ dst,
                            int* __restrict__ cursor, int* __restrict__ csr, int n) {
    const int e = blockIdx.x * 256 + threadIdx.x;
    if (e < n) {
        const int p = atomicAdd(&cursor[dst[e]], 1);
        csr[p] = src[e];
    }
}

// ---------- MFMA GEMM: C[M,N](f16) = A[M,K](f16) * Bt[N,K]^T + bias ----------
// 128x128 tile, 4 waves, BK=32, async global->LDS staging.
__global__ __launch_bounds__(256) void mgemm(
    const f16* __restrict__ A, int lda,
    const f16* __restrict__ Bt, int ldb,
    f16* __restrict__ C, int ldc,
    const float* __restrict__ bias,
    int M, int N, int K)
{
    __shared__ __attribute__((aligned(16))) f16 As[128 * 32];
    __shared__ __attribute__((aligned(16))) f16 Bs[128 * 32];
    const int tid  = threadIdx.x;
    const int lane = tid & 63;
    const int wave = tid >> 6;
    const int bm = blockIdx.x * 128;
    const int bn = blockIdx.y * 128;
    const int wm = (wave >> 1) * 64;
    const int wn = (wave & 1) * 64;
    const int quad = lane >> 4;
    const int l16  = lane & 15;

    floatx4 acc[4][4];
#pragma unroll
    for (int i = 0; i < 4; ++i)
#pragma unroll
        for (int j = 0; j < 4; ++j) acc[i][j] = (floatx4)(0.0f);

    for (int k0 = 0; k0 < K; k0 += 32) {
        __syncthreads();
#pragma unroll
        for (int it = 0; it < 2; ++it) {
            const int ci  = it * 256 + tid;   // 0..511
            const int row = ci >> 2;
            const int cg  = ci & 3;
            int ga = bm + row; if (ga > M - 1) ga = M - 1;
            gload_lds16(A + (long)ga * lda + k0 + cg * 8, As + ci * 8);
            gload_lds16(Bt + (long)(bn + row) * ldb + k0 + cg * 8, Bs + ci * 8);
        }
        __syncthreads();

        f16x8 af[4], bfv[4];
#pragma unroll
        for (int i = 0; i < 4; ++i) {
            af[i]  = *(const f16x8*)(As + (wm + i * 16 + l16) * 32 + quad * 8);
            bfv[i] = *(const f16x8*)(Bs + (wn + i * 16 + l16) * 32 + quad * 8);
        }
#pragma unroll
        for (int i = 0; i < 4; ++i)
#pragma unroll
            for (int j = 0; j < 4; ++j)
                acc[i][j] = mfma_16x16x32_f16(af[i], bfv[j], acc[i][j]);
    }

#pragma unroll
    for (int i = 0; i < 4; ++i) {
        const int r0 = bm + wm + i * 16 + quad * 4;
#pragma unroll
        for (int j = 0; j < 4; ++j) {
            const int col = bn + wn + j * 16 + l16;
            const float bv = bias ? bias[col] : 0.0f;
#pragma unroll
            for (int v = 0; v < 4; ++v) {
                const int r = r0 + v;
                if (r < M) C[(long)r * ldc + col] = (f16)(acc[i][j][v] + bv);
            }
        }
    }
}

// ---------- gates GEMM + fused GRU ----------
// A = agh rows [hsum | h] (K=512), B = Bb_s[1024][512], row = chblk*128+gate*32+c.
// BK=64, XOR bank-swizzle (chunk c of row r stored at slot c^(r&7); staging reads
// the permuted global chunk so the global_load_lds dest stays linear-in-lane).
// Gate-skip: k<256 computes gates {r,z,i_n}; k>=256 computes {r,z,h_n} (other
// halves of Bb are structurally zero). XCD swizzle: blockIdx%8 == rb%8.

#define GATES_STAGE(K0)                                                             \
    {                                                                               \
        __syncthreads();                                                            \
        _Pragma("unroll")                                                           \
        for (int it_ = 0; it_ < 4; ++it_) {                                         \
            const int ci_  = it_ * 256 + tid;                                       \
            const int row_ = ci_ >> 3;                                              \
            const int lc_  = (ci_ & 7) ^ (row_ & 7);                                \
            int ga_ = bm + row_; if (ga_ > M - 1) ga_ = M - 1;                      \
            gload_lds16(agh + (long)ga_ * 512 + (K0) + lc_ * 8, As + ci_ * 8);      \
            gload_lds16(Bb + (long)(cb * 128 + row_) * 512 + (K0) + lc_ * 8,        \
                        Bs + ci_ * 8);                                              \
        }                                                                           \
        __syncthreads();                                                            \
    }

#define GATES_STEP(KC, JJ)                                                          \
    {                                                                               \
        const int sl_ = (((KC) >> 3) + quad) ^ xr;                                  \
        f16x8 af_[4];                                                               \
        _Pragma("unroll")                                                           \
        for (int i_ = 0; i_ < 4; ++i_)                                              \
            af_[i_] = *(const f16x8*)(As + (wm + i_ * 16 + l16) * 64 + sl_ * 8);    \
        const f16x8 b0_ = *(const f16x8*)(Bs + (chh + l16) * 64 + sl_ * 8);         \
        const f16x8 b1_ = *(const f16x8*)(Bs + (32 + chh + l16) * 64 + sl_ * 8);    \
        const f16x8 b2_ = *(const f16x8*)(Bs + ((JJ) * 32 + chh + l16) * 64 + sl_ * 8); \
        _Pragma("unroll")                                                           \
        for (int i_ = 0; i_ < 4; ++i_) {                                            \
            acc[i_][0]    = mfma_16x16x32_f16(af_[i_], b0_, acc[i_][0]);            \
            acc[i_][1]    = mfma_16x16x32_f16(af_[i_], b1_, acc[i_][1]);            \
            acc[i_][(JJ)] = mfma_16x16x32_f16(af_[i_], b2_, acc[i_][(JJ)]);         \
        }                                                                           \
    }

__global__ __launch_bounds__(256) void gemm_gates(
    const f16* __restrict__ agh, const f16* __restrict__ Bb,
    f16* __restrict__ agh_nxt,
    const float* __restrict__ brz, const float* __restrict__ bin,
    const float* __restrict__ bhn, int M)
{
    const int lin = blockIdx.x;
    const int within = lin & 63;
    const int rb = (lin >> 6) * 8 + (within & 7);   // row block
    const int cb = within >> 3;                     // channel block 0..7
    if (rb * 128 >= M) return;

    __shared__ __attribute__((aligned(16))) f16 As[128 * 64];
    __shared__ __attribute__((aligned(16))) f16 Bs[128 * 64];
    const int tid  = threadIdx.x;
    const int lane = tid & 63;
    const int wave = tid >> 6;
    const int bm = rb * 128;
    const int wm  = (wave >> 1) * 64;
    const int chh = (wave & 1) * 16;      // channel half within block
    const int quad = lane >> 4;
    const int l16  = lane & 15;
    const int xr   = l16 & 7;
    const int kcap0 = 256 + ((cb * 32) & ~63);  // K-iter holding this block's h cols
    const int koff  = (cb & 1) * 32;            // column offset within that tile

    floatx4 acc[4][4];
#pragma unroll
    for (int i = 0; i < 4; ++i)
#pragma unroll
        for (int j = 0; j < 4; ++j) acc[i][j] = (floatx4)(0.0f);
    f16 h_frag[4][4] = {};

    // half 0: k in [0,256) -> gates r,z,i_n
    for (int k0 = 0; k0 < 256; k0 += 64) {
        GATES_STAGE(k0)
        GATES_STEP(0, 2)
        GATES_STEP(32, 2)
    }
    // half 1: k in [256,512) -> gates r,z,h_n (+ capture h fragment from LDS)
    for (int k0 = 256; k0 < 512; k0 += 64) {
        GATES_STAGE(k0)
        if (k0 == kcap0) {
#pragma unroll
            for (int i = 0; i < 4; ++i)
#pragma unroll
                for (int v = 0; v < 4; ++v) {
                    const int r = wm + i * 16 + quad * 4 + v;
                    const int kcol = koff + chh + l16;
                    const int slot = (kcol >> 3) ^ (r & 7);
                    h_frag[i][v] = As[r * 64 + slot * 8 + (kcol & 7)];
                }
        }
        GATES_STEP(0, 3)
        GATES_STEP(32, 3)
    }

    // epilogue: lane owns channel ch; acc[i][g][v] = gate g preact at row r0+v
    const int ch = cb * 32 + chh + l16;
    const float b_r  = brz[ch];
    const float b_z  = brz[256 + ch];
    const float b_in = bin[ch];
    const float b_hn = bhn[ch];
#pragma unroll
    for (int i = 0; i < 4; ++i) {
        const int r0 = bm + wm + i * 16 + quad * 4;
#pragma unroll
        for (int v = 0; v < 4; ++v) {
            const int r = r0 + v;
            if (r < M) {
                const float rg = sigm(acc[i][0][v] + b_r);
                const float zg = sigm(acc[i][1][v] + b_z);
                const float nn = tanh_fast(acc[i][2][v] + b_in + rg * (acc[i][3][v] + b_hn));
                const float ho = (float)h_frag[i][v];
                agh_nxt[(long)r * 512 + 256 + ch] = (f16)((1.0f - zg) * nn + zg * ho);
            }
        }
    }
}

// ---------- aggregate: agh[v][0:256] = sum_{e: dst=v} agh[src[e]][256:512] ----------
// half-wave (32 lanes x f16x8 = 512B row) per node
__global__ __launch_bounds__(256) void aggregate(
    f16* __restrict__ agh, const int* __restrict__ row_off, const int* __restrict__ csr)
{
    const int node = blockIdx.x * 8 + (threadIdx.x >> 5);
    const int lane = threadIdx.x & 31;
    if (node >= N_NODES) return;
    const int e0 = row_off[node], e1 = row_off[node + 1];
    float a[8] = {0.0f, 0.0f, 0.0f, 0.0f, 0.0f, 0.0f, 0.0f, 0.0f};
    for (int e = e0; e < e1; ++e) {
        const int s = csr[e];
        const f16x8 v = *(const f16x8*)(agh + (long)s * 512 + 256 + lane * 8);
#pragma unroll
        for (int u = 0; u < 8; ++u) a[u] += (float)v[u];
    }
    f16x8 o;
#pragma unroll
    for (int u = 0; u < 8; ++u) o[u] = (f16)a[u];
    *(f16x8*)(agh + (long)node * 512 + lane * 8) = o;
}

// ---------- final head ----------
__global__ __launch_bounds__(256) void final_kernel(
    const f16* __restrict__ h, const float* __restrict__ wlin,
    const float* __restrict__ blin, void* __restrict__ out,
    const int* __restrict__ flagp)
{
    const int flag = *flagp;
    const int node = blockIdx.x * 4 + (threadIdx.x >> 6);
    const int lane = threadIdx.x & 63;
    if (node >= N_NODES) return;
    const f16* hp = h + (long)node * 512;
    float a0 = 0.0f, a1 = 0.0f;
#pragma unroll
    for (int u = 0; u < 4; ++u) {
        const int c = lane * 4 + u;
        float hv = (float)hp[c];
        hv = hv > 0.0f ? hv : 0.0f;
        a0 += hv * wlin[c];
        a1 += hv * wlin[256 + c];
    }
#pragma unroll
    for (int off = 32; off > 0; off >>= 1) {
        a0 += __shfl_down(a0, off);
        a1 += __shfl_down(a1, off);
    }
    if (lane == 0) {
        a0 += blin[0];
        a1 += blin[1];
        const float mx  = fmaxf(a0, a1);
        const float lse = mx + logf(expf(a0 - mx) + expf(a1 - mx));
        const float o0 = a0 - lse, o1 = a1 - lse;
        if (flag) {
            ((float*)out)[(long)node * 2]     = o0;
            ((float*)out)[(long)node * 2 + 1] = o1;
        } else {
            ((u16*)out)[(long)node * 2]     = f32_to_bf_bits(o0);
            ((u16*)out)[(long)node * 2 + 1] = f32_to_bf_bits(o1);
        }
    }
}

extern "C" void kernel_launch(void* const* d_in, const int* in_sizes, int n_in,
                              void* d_out, int out_size, void* d_ws, size_t ws_size,
                              hipStream_t stream)
{
    (void)in_sizes; (void)n_in; (void)out_size; (void)ws_size;
    const void* x        = d_in[0];
    const int*  ei       = (const int*)d_in[1];
    const void* W_reduce = d_in[3];
    const void* b_reduce = d_in[4];
    const void* W_ggc    = d_in[5];
    const void* W_ih     = d_in[6];
    const void* W_hh     = d_in[7];
    const void* b_ih     = d_in[8];
    const void* b_hh     = d_in[9];
    const void* W_lin    = d_in[10];
    const void* b_lin    = d_in[11];
    const int* src = ei;
    const int* dst = ei + N_EDGES;

    char* w = (char*)d_ws;
    auto carve = [&](size_t bytes) -> char* {
        char* p = w;
        w += (bytes + 255) & ~(size_t)255;
        return p;
    };
    // agh layout: [N][512] f16; cols 0..255 = hsum, 256..511 = h
    f16* agh_a = (f16*)carve((size_t)N_NODES * 512 * 2);
    f16* agh_b = (f16*)carve((size_t)N_NODES * 512 * 2);   // union with x_cvt [N,KXP]
    f16* x_cvt = agh_b;   // dead before agh_b's first write (gates s=0)
    f16*   WrT   = (f16*)carve((size_t)256 * KXP * 2);
    f16*   Wih16 = (f16*)carve((size_t)768 * 256 * 2);
    f16*   Wg16  = (f16*)carve((size_t)2048 * 256 * 2);
    f16*   Wc    = (f16*)carve((size_t)768 * 2048 * 2);
    f16*   Bb8   = (f16*)carve((size_t)8 * 1024 * 512 * 2);
    float* sp    = (float*)carve(2048 * 4);
    int*   flag  = (int*)carve(256);
    int* deg     = (int*)carve((size_t)N_NODES * 4);
    int* row_off = (int*)carve((size_t)(N_NODES + 1) * 4);
    int* cursor  = (int*)carve((size_t)N_NODES * 4);
    int* csr     = (int*)carve((size_t)N_EDGES * 4);
    int* partial = (int*)carve(256 * 4);

    float* brz  = sp;
    float* bin  = sp + 512;
    float* bhn  = sp + 768;
    float* br0  = sp + 1024;
    float* wlin = sp + 1280;
    float* blin = sp + 1792;

    probe_dtype<<<1, 64, 0, stream>>>((const u32*)x, flag);

    cvt_f16<<<(768 * 256 + 255) / 256, 256, 0, stream>>>(W_ih, Wih16, 768 * 256, flag);
    cvt_f16<<<(2048 * 256 + 255) / 256, 256, 0, stream>>>(W_ggc, Wg16, 2048 * 256, flag);
    build_wrT<<<(256 * KXP + 255) / 256, 256, 0, stream>>>(W_reduce, WrT, flag);
    build_small<<<8, 256, 0, stream>>>(b_ih, b_hh, b_reduce, W_lin, b_lin, sp, flag);
    build_xcvt<<<(int)(((long)N_NODES * KXP + 255) / 256), 256, 0, stream>>>(x, x_cvt, flag);

    zero_i32<<<196, 256, 0, stream>>>(deg, N_NODES);
    hist_kernel<<<(N_EDGES + 255) / 256, 256, 0, stream>>>(dst, deg, N_EDGES);
    block_sum<<<196, 256, 0, stream>>>(deg, partial, N_NODES);
    scan_partials<<<1, 256, 0, stream>>>(partial, 196, row_off + N_NODES);
    scan_block<<<196, 256, 0, stream>>>(deg, partial, row_off, cursor, N_NODES);
    fill_kernel<<<(N_EDGES + 255) / 256, 256, 0, stream>>>(src, dst, cursor, csr, N_EDGES);

    // Wc[c][s*256+k] = sum_n Wih[c][n] * Wg_s[k][n]  (one GEMM: M=768, N=2048, K=256)
    mgemm<<<dim3(6, 16), 256, 0, stream>>>(Wih16, 256, Wg16, 256, Wc, 2048,
                                           (const float*)nullptr, 768, 2048, 256);
    build_bb8<<<(8 * 1024 * 512) / 256, 256, 0, stream>>>(Wc, W_hh, Bb8, flag);

    // h0 = x @ W_reduce^T + b_reduce -> agh_a cols 256..511
    mgemm<<<dim3(391, 2), 256, 0, stream>>>(x_cvt, KXP, WrT, KXP, agh_a + 256, 512, br0,
                                            N_NODES, 256, KXP);

    for (int s = 0; s < 8; ++s) {
        f16* cur = (s & 1) ? agh_b : agh_a;
        f16* nxt = (s & 1) ? agh_a : agh_b;
        aggregate<<<6250, 256, 0, stream>>>(cur, row_off, csr);
        gemm_gates<<<49 * 64, 256, 0, stream>>>(cur, Bb8 + (size_t)s * 524288, nxt,
                                                brz, bin, bhn, N_NODES);
    }

    // after s=7, h is in agh_a cols 256..511
    final_kernel<<<12500, 256, 0, stream>>>(agh_a + 256, wlin, blin, d_out, flag);
}